// Round 10
// baseline (999.779 us; speedup 1.0000x reference)
//
#include <hip/hip_runtime.h>

#define H 64
#define NE 1500000
#define NLOC 20000
#define NEXP 200000
#define NL 400000
#define PAD_E 32
#define PAD_L 128

// ---- bucket-sort fill geometry ----
#define EB 896
#define NBE 224
#define LB 112
#define NBL 179
#define BIN_CHUNK 2048
#define NBIN ((NE + BIN_CHUNK - 1) / BIN_CHUNK)   // 733
#define EBSLOT 28
#define LBSLOT 32
#define ECAP 8192
#define LCAP 10240
#define FCAP 4096

// ---- workspace layout (bytes) ----
// cnt_loc [0,80000)  cnt_exp [80000,880000)
// nbr_loc [880064,11120064)  nbr_exp(u16) [11120064,23920064)
// Ylh(f16)  [23920064,26480064)   Y2fh(f16) [26480064,29040064)
// (z_loc region now unused)       PH(f16)   [34160064,36720064)
// weights hole: W1rT16 +8192 | W1lrT16 | WfqT16 | W1rRevH16 | Wt2H16 |
//               WpH16 | Wy2H16 [36777472,+8192)
// ZT(f16, 256B interleaved rows [ZE|TH]) [39280064,90480064)  (51.2MB exact)
//   (aliased pre-passA: expQ/locQ/qcnt/flbk/flbkQ)
// Wf_q [90480064) Wf_y2 [90496448) Wf_t2 [90512832) Wf_p [90529216)
// bf_q [90545600) bf_p [90545856)
#define WS_NEED 90546112ULL

typedef int vint4 __attribute__((ext_vector_type(4)));
typedef _Float16 f16x8 __attribute__((ext_vector_type(8)));
typedef _Float16 f16x4 __attribute__((ext_vector_type(4)));
typedef float f32x4 __attribute__((ext_vector_type(4)));
typedef unsigned int u32;
typedef unsigned short u16;
typedef unsigned long long u64;

__device__ __forceinline__ float bcastf(float v, int k) {
  return __int_as_float(__builtin_amdgcn_readlane(__float_as_int(v), k));
}
__device__ __forceinline__ int bcasti(int v, int k) {
  return __builtin_amdgcn_readlane(v, k);
}
__device__ __forceinline__ int sel4(int g, int n0, int n1, int n2, int n3) {
  return (g & 2) ? ((g & 1) ? n3 : n2) : ((g & 1) ? n1 : n0);
}
__device__ __forceinline__ float sel4f(int g, float a, float b, float c, float d) {
  return (g & 2) ? ((g & 1) ? d : c) : ((g & 1) ? b : a);
}
__device__ __forceinline__ float sel8f(int i, float a, float b, float c, float d,
                                       float e, float f, float g2, float h2) {
  return (i & 4) ? sel4f(i & 3, e, f, g2, h2) : sel4f(i & 3, a, b, c, d);
}

// ---------------- bucket-sort fill, pass 1: bin edges ----------------
__global__ __launch_bounds__(256) void bin_kernel(
    const int* __restrict__ src, const int* __restrict__ dst,
    u32* __restrict__ expQ, u32* __restrict__ locQ,
    int* __restrict__ qcnt, int* __restrict__ flbk_cnt,
    u64* __restrict__ flbkQ)
{
  __shared__ u32 eb[NBE * EBSLOT];
  __shared__ u32 lb[NBL * LBSLOT];
  __shared__ int ec[NBE], lc[NBL], ebase[NBE], lbase[NBL];

  const int tid = threadIdx.x;
  for (int i = tid; i < NBE; i += 256) ec[i] = 0;
  for (int i = tid; i < NBL; i += 256) lc[i] = 0;
  __syncthreads();

  const long base = (long)blockIdx.x * BIN_CHUNK + tid * 8;
  if (base < NE) {
    vint4 s0 = __builtin_nontemporal_load((const vint4*)(src + base));
    vint4 s1 = __builtin_nontemporal_load((const vint4*)(src + base + 4));
    vint4 d0 = __builtin_nontemporal_load((const vint4*)(dst + base));
    vint4 d1 = __builtin_nontemporal_load((const vint4*)(dst + base + 4));
    int ss[8] = {s0.x, s0.y, s0.z, s0.w, s1.x, s1.y, s1.z, s1.w};
    int dd[8] = {d0.x, d0.y, d0.z, d0.w, d1.x, d1.y, d1.z, d1.w};
#pragma unroll
    for (int k = 0; k < 8; k++) {
      const u32 d = (u32)dd[k], s = (u32)ss[k];
      {
        const u32 b = d / (u32)EB;
        const int pos = atomicAdd(&ec[b], 1);
        if (pos < EBSLOT) {
          eb[b * EBSLOT + pos] = ((d - b * EB) << 16) | s;
        } else {
          int fi = atomicAdd(flbk_cnt, 1);
          if (fi < FCAP) flbkQ[fi] = ((u64)d << 32) | (u64)s;
        }
      }
      {
        const u32 b = s / (u32)LB;
        const int pos = atomicAdd(&lc[b], 1);
        if (pos < LBSLOT) {
          lb[b * LBSLOT + pos] = ((s - b * LB) << 18) | d;
        } else {
          int fi = atomicAdd(flbk_cnt, 1);
          if (fi < FCAP) flbkQ[fi] = (1ULL << 63) | ((u64)s << 32) | (u64)d;
        }
      }
    }
  }
  __syncthreads();

  for (int i = tid; i < NBE; i += 256) {
    const int c = min(ec[i], EBSLOT);
    ebase[i] = c ? atomicAdd(&qcnt[i], c) : 0;
  }
  for (int i = tid; i < NBL; i += 256) {
    const int c = min(lc[i], LBSLOT);
    lbase[i] = c ? atomicAdd(&qcnt[NBE + i], c) : 0;
  }
  __syncthreads();

  const int wid = tid >> 6, ln = tid & 63;
  for (int b = wid; b < NBE; b += 4) {
    const int c = min(ec[b], EBSLOT);
    if (ln < c) {
      const int idx = ebase[b] + ln;
      const u32 r = eb[b * EBSLOT + ln];
      if (idx < ECAP) {
        expQ[(long)b * ECAP + idx] = r;
      } else {
        int fi = atomicAdd(flbk_cnt, 1);
        if (fi < FCAP)
          flbkQ[fi] = ((u64)(b * EB + (r >> 16)) << 32) | (u64)(r & 0xFFFF);
      }
    }
  }
  for (int b = wid; b < NBL; b += 4) {
    const int c = min(lc[b], LBSLOT);
    if (ln < c) {
      const int idx = lbase[b] + ln;
      const u32 r = lb[b * LBSLOT + ln];
      if (idx < LCAP) {
        locQ[(long)b * LCAP + idx] = r;
      } else {
        int fi = atomicAdd(flbk_cnt, 1);
        if (fi < FCAP)
          flbkQ[fi] = (1ULL << 63) | ((u64)(b * LB + (r >> 18)) << 32) |
                      (u64)(r & 0x3FFFF);
      }
    }
  }
}

// ---------------- bucket-sort fill, pass 2: build padded CSR ----------------
// loc rows SORTED by expert id (bitonic = min/max network -> always a
// permutation, so results are sort-correctness-independent; order only
// affects locality). Pads 0x3FFFF sort to the end.
__global__ __launch_bounds__(256) void build_kernel(
    const u32* __restrict__ expQ, const u32* __restrict__ locQ,
    const int* __restrict__ qcnt,
    u16* __restrict__ nbr_exp, int* __restrict__ nbr_loc,
    int* __restrict__ cnt_exp, int* __restrict__ cnt_loc)
{
  __shared__ char ldsraw[60928];
  const int tid = threadIdx.x;
  if (blockIdx.x < NBE) {
    const int b = blockIdx.x;
    u16* rows = (u16*)ldsraw;
    int* cnts = (int*)(ldsraw + 57344);
    for (int i = tid; i < EB; i += 256) cnts[i] = 0;
    __syncthreads();
    const int n = min(qcnt[b], ECAP);
    for (int i = tid; i < n; i += 256) {
      const u32 r = expQ[(long)b * ECAP + i];
      const int nl = (int)(r >> 16);
      const int pos = atomicAdd(&cnts[nl], 1);
      if (pos < PAD_E) rows[nl * PAD_E + pos] = (u16)(r & 0xFFFF);
    }
    __syncthreads();
    const int node0 = b * EB;
    const int nn = min(EB, NEXP - node0);
    u32* grows = (u32*)(nbr_exp + (long)node0 * PAD_E);
    const u32* lrows = (const u32*)rows;
    for (int j = tid; j < nn * (PAD_E / 2); j += 256) grows[j] = lrows[j];
    for (int i = tid; i < nn; i += 256) cnt_exp[node0 + i] = cnts[i];
  } else {
    const int b = blockIdx.x - NBE;
    int* rows = (int*)ldsraw;
    int* cnts = (int*)(ldsraw + 57344);
    for (int i = tid; i < LB; i += 256) cnts[i] = 0;
    for (int i = tid; i < LB * PAD_L; i += 256) rows[i] = 0x3FFFF;  // pad
    __syncthreads();
    const int n = min(qcnt[NBE + b], LCAP);
    for (int i = tid; i < n; i += 256) {
      const u32 r = locQ[(long)b * LCAP + i];
      const int sl = (int)(r >> 18);
      const int pos = atomicAdd(&cnts[sl], 1);
      if (pos < PAD_L) rows[sl * PAD_L + pos] = (int)(r & 0x3FFFF);
    }
    __syncthreads();
    const int ln = tid & 63, wd = tid >> 6;
    for (int r = wd; r < LB; r += 4) {
      int* row = rows + r * PAD_L;
      int v0 = row[ln], v1 = row[64 + ln];
      for (int k = 2; k <= 128; k <<= 1) {
        for (int j = k >> 1; j >= 1; j >>= 1) {
          if (j == 64) {
            const int a = min(v0, v1), bmx = max(v0, v1);
            v0 = a; v1 = bmx;
          } else {
            const int p0 = __shfl_xor(v0, j);
            const int p1 = __shfl_xor(v1, j);
            const bool up = ((ln & j) == 0);
            const bool a0 = ((ln & k) == 0);
            const bool a1 = (((ln + 64) & k) == 0);
            v0 = (up == a0) ? min(v0, p0) : max(v0, p0);
            v1 = (up == a1) ? min(v1, p1) : max(v1, p1);
          }
        }
      }
      row[ln] = v0; row[64 + ln] = v1;
    }
    __syncthreads();
    const int node0 = b * LB;
    const int nn = min(LB, NLOC - node0);
    int* grows = nbr_loc + (long)node0 * PAD_L;
    for (int j = tid; j < nn * PAD_L; j += 256) grows[j] = rows[j];
    for (int i = tid; i < nn; i += 256) cnt_loc[node0 + i] = cnts[i];
  }
}

// prep_kernel: folds + f16 weight copies + fallback drain + dense Ylh.
__global__ __launch_bounds__(256) void prep_kernel(
    const float* __restrict__ W2r_of, const float* __restrict__ W2l_of,
    const float* __restrict__ W2l_rev, const float* __restrict__ W2r_rev,
    const float* __restrict__ dW1, const float* __restrict__ b2_of,
    const float* __restrict__ b2_rev,
    float* __restrict__ Wf_q, float* __restrict__ Wf_y2,
    float* __restrict__ Wf_t2, float* __restrict__ Wf_p,
    float* __restrict__ bf_q, float* __restrict__ bf_p,
    const int* __restrict__ flbk_cnt, const u64* __restrict__ flbkQ,
    u16* __restrict__ nbr_exp, int* __restrict__ nbr_loc,
    int* __restrict__ cnt_exp, int* __restrict__ cnt_loc,
    const float* __restrict__ emb_loc, _Float16* __restrict__ Ylh,
    const float* __restrict__ W1l_of,
    const float* __restrict__ W1r_of, const float* __restrict__ W1l_rev,
    const float* __restrict__ W1r_rev,
    _Float16* __restrict__ W1rT16, _Float16* __restrict__ W1lrT16,
    _Float16* __restrict__ WfqT16,
    _Float16* __restrict__ W1rRevH16, _Float16* __restrict__ Wt2H16,
    _Float16* __restrict__ WpH16, _Float16* __restrict__ Wy2H16)
{
  const int lane = threadIdx.x & 63;
  const int w = threadIdx.x >> 6;
  const float* dW1a = dW1;
  const float* dW1b = dW1 + H * H;
  if (blockIdx.x < 4) {
    const float* A; const float* B; float* C;
    _Float16* CT; _Float16* CH;
    switch (blockIdx.x) {
      case 0:  A = W2r_of;  B = dW1b; C = Wf_q;  CT = WfqT16; CH = nullptr; break;
      case 1:  A = W2l_of;  B = dW1b; C = Wf_y2; CT = nullptr; CH = Wy2H16; break;
      case 2:  A = W2l_rev; B = dW1a; C = Wf_t2; CT = nullptr; CH = Wt2H16; break;
      default: A = W2r_rev; B = dW1a; C = Wf_p;  CT = nullptr; CH = WpH16;  break;
    }
    float b[H];
#pragma unroll
    for (int k = 0; k < H; k++) b[k] = B[k * H + lane];
    for (int r = w * 16; r < w * 16 + 16; r++) {
      const float xv = A[r * H + lane];
      float a0 = 0.f, a1 = 0.f;
#pragma unroll
      for (int k = 0; k < H; k += 2) {
        a0 += bcastf(xv, k)     * b[k];
        a1 += bcastf(xv, k + 1) * b[k + 1];
      }
      const float val = a0 + a1;
      C[r * H + lane] = val;
      if (CT) CT[(long)lane * H + r] = (_Float16)val;
      if (CH) CH[(long)r * H + lane] = (_Float16)val;
    }
  } else if (blockIdx.x == 4) {
    if (w < 2) {
      const float* bv_src = (w == 0) ? b2_of : b2_rev;
      const float* B      = (w == 0) ? dW1b  : dW1a;
      float* o            = (w == 0) ? bf_q  : bf_p;
      float wk[H];
#pragma unroll
      for (int k = 0; k < H; k++) wk[k] = B[k * H + lane];
      const float bv = bv_src[lane];
      float a = 0.f;
#pragma unroll
      for (int k = 0; k < H; k++) a += bcastf(bv, k) * wk[k];
      o[lane] = a;
    }
  } else if (blockIdx.x == 5) {
    const int n = min(*flbk_cnt, FCAP);
    for (int i = threadIdx.x; i < n; i += 256) {
      const u64 rec = flbkQ[i];
      const int node = (int)((rec >> 32) & 0x3FFFF);
      const int val  = (int)(rec & 0x3FFFF);
      if ((rec >> 63) == 0) {
        int pos = atomicAdd(&cnt_exp[node], 1);
        if (pos < PAD_E) nbr_exp[(long)node * PAD_E + pos] = (u16)val;
      } else {
        int pos = atomicAdd(&cnt_loc[node], 1);
        if (pos < PAD_L) nbr_loc[(long)node * PAD_L + pos] = val;
      }
    }
  } else if (blockIdx.x < 8) {
    const float* S = (blockIdx.x == 6) ? W1r_of : W1l_rev;
    _Float16* D    = (blockIdx.x == 6) ? W1rT16 : W1lrT16;
    for (int k = w * 16; k < w * 16 + 16; k++)
      D[(long)lane * H + k] = (_Float16)S[(long)k * H + lane];
  } else if (blockIdx.x == 8) {
    for (int k = w * 16; k < w * 16 + 16; k++)
      W1rRevH16[(long)k * H + lane] = (_Float16)W1r_rev[(long)k * H + lane];
  } else {
    float wreg[H];
#pragma unroll
    for (int k = 0; k < H; k++) wreg[k] = W1l_of[k * H + lane];
    const int gw2 = (blockIdx.x - 9) * 4 + w;       // 0..4999
    for (int r = gw2; r < NLOC; r += 5000) {
      const float xv = emb_loc[(long)r * H + lane];
      float a0 = 0.f, a1 = 0.f;
#pragma unroll
      for (int k = 0; k < H; k += 2) {
        a0 += bcastf(xv, k)     * wreg[k];
        a1 += bcastf(xv, k + 1) * wreg[k + 1];
      }
      Ylh[(long)r * H + lane] = (_Float16)(a0 + a1);
    }
  }
}

// Exp-side MFMA pass (dual-B optional, gather/bias/relu optional).
// r10: stride params so outputs can interleave into the ZT table.
__global__ __launch_bounds__(256, 4) void mfma_pass_kernel(
    const u16* __restrict__ nbr, const int* __restrict__ cnt,
    const _Float16* __restrict__ y,
    const float* a32, const _Float16* a16, int sa,
    _Float16* out1, int s1, const _Float16* __restrict__ W1T,
    const float* __restrict__ bias, int relu,
    _Float16* out2, int s2, const _Float16* __restrict__ W2T)
{
  const int w = threadIdx.x >> 6;
  const int lane = threadIdx.x & 63;
  const int q = lane >> 4;
  const int cidx = lane & 15;
  const int rb = blockIdx.x * 16;

  __shared__ float Gs[16 * 68];

  const _Float16* bt1 = W1T + (long)(w * 16 + cidx) * H;
  f16x8 b1lo = *(const f16x8*)(bt1 + q * 8);
  f16x8 b1hi = *(const f16x8*)(bt1 + 32 + q * 8);
  f16x8 b2lo, b2hi;
  if (out2) {
    const _Float16* bt2 = W2T + (long)(w * 16 + cidx) * H;
    b2lo = *(const f16x8*)(bt2 + q * 8);
    b2hi = *(const f16x8*)(bt2 + 32 + q * 8);
  }

  f16x8 a0, a1;
  if (a16) {
    const _Float16* ar = a16 + (long)(rb + cidx) * sa;
    a0 = *(const f16x8*)(ar + q * 8);
    a1 = *(const f16x8*)(ar + 32 + q * 8);
  } else {
    const float* ar = a32 + (long)(rb + cidx) * H;
    f32x4 v0 = *(const f32x4*)(ar + q * 8);
    f32x4 v1 = *(const f32x4*)(ar + q * 8 + 4);
    f32x4 v2 = *(const f32x4*)(ar + 32 + q * 8);
    f32x4 v3 = *(const f32x4*)(ar + 32 + q * 8 + 4);
#pragma unroll
    for (int j = 0; j < 4; j++) {
      a0[j] = (_Float16)v0[j];
      a0[j + 4] = (_Float16)v1[j];
      a1[j] = (_Float16)v2[j];
      a1[j + 4] = (_Float16)v3[j];
    }
  }

  if (y) {
    const int i0r = rb + w * 4;
    const int g = lane >> 4;
    const int sub = lane & 15;
    int c4v[4];
#pragma unroll
    for (int rr = 0; rr < 4; rr++) c4v[rr] = cnt[i0r + rr];
    int id4[4];
#pragma unroll
    for (int rr = 0; rr < 4; rr++) {
      const int c = min(c4v[rr], PAD_E);
      id4[rr] = (lane < c) ? (int)nbr[(long)(i0r + rr) * PAD_E + lane] : 0;
    }
#pragma unroll
    for (int rr = 0; rr < 4; rr++) {
      const int cc = min(c4v[rr], PAD_E);
      const int id = id4[rr];
      const int kl = cc - 1;
      float s0 = 0.f, s1v = 0.f, s2v = 0.f, s3 = 0.f;
      for (int k = 0; k < cc; k += 4) {
        const int n0 = bcasti(id, k);
        const int n1 = bcasti(id, min(k + 1, kl));
        const int n2 = bcasti(id, min(k + 2, kl));
        const int n3 = bcasti(id, min(k + 3, kl));
        const int ns = sel4(g, n0, n1, n2, n3);
        const f16x4 v = *(const f16x4*)(y + (long)ns * H + sub * 4);
        const float msk = (k + g < cc) ? 1.0f : 0.0f;
        s0 = fmaf(msk, (float)v[0], s0);
        s1v = fmaf(msk, (float)v[1], s1v);
        s2v = fmaf(msk, (float)v[2], s2v);
        s3 = fmaf(msk, (float)v[3], s3);
      }
      s0 += __shfl_xor(s0, 16); s0 += __shfl_xor(s0, 32);
      s1v += __shfl_xor(s1v, 16); s1v += __shfl_xor(s1v, 32);
      s2v += __shfl_xor(s2v, 16); s2v += __shfl_xor(s2v, 32);
      s3 += __shfl_xor(s3, 16); s3 += __shfl_xor(s3, 32);
      const float inv = 1.0f / fmaxf((float)c4v[rr], 1.0f);
      if (lane < 16) {
        float* gp = &Gs[(w * 4 + rr) * 68 + 4 * lane];
        gp[0] = s0 * inv; gp[1] = s1v * inv;
        gp[2] = s2v * inv; gp[3] = s3 * inv;
      }
    }
  }

  f32x4 acc1 = {0.f, 0.f, 0.f, 0.f};
  acc1 = __builtin_amdgcn_mfma_f32_16x16x32_f16(a0, b1lo, acc1, 0, 0, 0);
  acc1 = __builtin_amdgcn_mfma_f32_16x16x32_f16(a1, b1hi, acc1, 0, 0, 0);
  f32x4 acc2 = {0.f, 0.f, 0.f, 0.f};
  if (out2) {
    acc2 = __builtin_amdgcn_mfma_f32_16x16x32_f16(a0, b2lo, acc2, 0, 0, 0);
    acc2 = __builtin_amdgcn_mfma_f32_16x16x32_f16(a1, b2hi, acc2, 0, 0, 0);
  }

  const float bj = bias ? bias[w * 16 + cidx] : 0.f;
  __syncthreads();
#pragma unroll
  for (int reg = 0; reg < 4; reg++) {
    const int r = q * 4 + reg;
    float v = acc1[reg] + bj;
    if (y) v += Gs[r * 68 + w * 16 + cidx];
    if (relu) v = fmaxf(v, 0.f);
    out1[(long)(rb + r) * s1 + w * 16 + cidx] = (_Float16)v;
    if (out2)
      out2[(long)(rb + r) * s2 + w * 16 + cidx] = (_Float16)acc2[reg];
  }
}

// Fused loc pass over the interleaved ZT table: one sorted walk serves BOTH
// gathers (TH-half -> z; ZE-half -> gz). Groups walk the 4 QUARTERS of the
// SAME row (r8-proven reduce); sorted quarters = 4 narrow expert bands.
// 4 synchronized epochs of 5000 rows keep all waves in the same bands.
// Epilogue: z = relu(g1 + x@W1rRev + b1); Y2fh = z@Wy2; PH = gz@Wt2+z@Wp+bp.
__global__ __launch_bounds__(256, 5) void loc_fused_kernel(
    const int* __restrict__ nbr, const int* __restrict__ cnt,
    const _Float16* __restrict__ ZT, const float* __restrict__ x,
    _Float16* __restrict__ y2_out, _Float16* __restrict__ ph_out,
    const _Float16* __restrict__ Wr16, const _Float16* __restrict__ Wy216,
    const _Float16* __restrict__ Wt216, const _Float16* __restrict__ Wp16,
    const float* __restrict__ b1, const float* __restrict__ bfp)
{
  __shared__ _Float16 Wl[4 * 4096];   // 32KB -> 5 blocks/CU
  const int tid = threadIdx.x;
  for (int j = tid * 8; j < 4096; j += 2048) {
    *(f16x8*)&Wl[j]         = *(const f16x8*)&Wr16[j];
    *(f16x8*)&Wl[4096 + j]  = *(const f16x8*)&Wy216[j];
    *(f16x8*)&Wl[8192 + j]  = *(const f16x8*)&Wt216[j];
    *(f16x8*)&Wl[12288 + j] = *(const f16x8*)&Wp16[j];
  }
  __syncthreads();

  const int lane = tid & 63;
  const int gw = (blockIdx.x * 256 + tid) >> 6;   // 0..4999
  const int g = lane >> 4, sub = lane & 15;
  const float bj = b1[lane];
  const float bp = bfp[lane];

  for (int ep = 0; ep < 4; ep++) {
    const int i = gw + ep * 5000;
    const int cf = cnt[i];
    const int cc = min(cf, PAD_L);
    const int qlen = (cc + 3) >> 2;               // quarter length <= 32
    const int* nb = nbr + (long)i * PAD_L;
    const int k0 = g * qlen;
    // preload group g's quarter ids (sorted; pads clamp to NEXP-1)
    const int idq0 = min(nb[min(k0 + sub, PAD_L - 1)], NEXP - 1);
    const int idq1 = min(nb[min(k0 + 16 + sub, PAD_L - 1)], NEXP - 1);

    float a0 = 0.f, a1 = 0.f, a2 = 0.f, a3 = 0.f;
    float a4 = 0.f, a5 = 0.f, a6 = 0.f, a7 = 0.f;
    for (int t = 0; t < qlen; t++) {
      const int idv = (t < 16) ? idq0 : idq1;     // t wave-uniform
      const int e = __shfl(idv, (lane & 48) + (t & 15));
      const float ms = (k0 + t < cc) ? 1.0f : 0.0f;
      const f16x8 v = *(const f16x8*)(ZT + (long)e * 128 + sub * 8);
      a0 = fmaf(ms, (float)v[0], a0);
      a1 = fmaf(ms, (float)v[1], a1);
      a2 = fmaf(ms, (float)v[2], a2);
      a3 = fmaf(ms, (float)v[3], a3);
      a4 = fmaf(ms, (float)v[4], a4);
      a5 = fmaf(ms, (float)v[5], a5);
      a6 = fmaf(ms, (float)v[6], a6);
      a7 = fmaf(ms, (float)v[7], a7);
    }
    // reduce the 4 quarters (same row) across groups
    a0 += __shfl_xor(a0, 16); a0 += __shfl_xor(a0, 32);
    a1 += __shfl_xor(a1, 16); a1 += __shfl_xor(a1, 32);
    a2 += __shfl_xor(a2, 16); a2 += __shfl_xor(a2, 32);
    a3 += __shfl_xor(a3, 16); a3 += __shfl_xor(a3, 32);
    a4 += __shfl_xor(a4, 16); a4 += __shfl_xor(a4, 32);
    a5 += __shfl_xor(a5, 16); a5 += __shfl_xor(a5, 32);
    a6 += __shfl_xor(a6, 16); a6 += __shfl_xor(a6, 32);
    a7 += __shfl_xor(a7, 16); a7 += __shfl_xor(a7, 32);
    // redistribute: col j=lane. ZE col j from lane (j>>3) elem (j&7);
    // TH col j from lane 8+(j>>3) elem (j&7).
    const int zsrc = lane >> 3;
    const int tsrc = 8 + (lane >> 3);
    const float z0 = __shfl(a0, zsrc), z1 = __shfl(a1, zsrc);
    const float z2 = __shfl(a2, zsrc), z3 = __shfl(a3, zsrc);
    const float z4 = __shfl(a4, zsrc), z5 = __shfl(a5, zsrc);
    const float z6 = __shfl(a6, zsrc), z7 = __shfl(a7, zsrc);
    const float t0 = __shfl(a0, tsrc), t1 = __shfl(a1, tsrc);
    const float t2 = __shfl(a2, tsrc), t3 = __shfl(a3, tsrc);
    const float t4 = __shfl(a4, tsrc), t5 = __shfl(a5, tsrc);
    const float t6 = __shfl(a6, tsrc), t7 = __shfl(a7, tsrc);
    const int r3 = lane & 7;
    const float inv = 1.0f / fmaxf((float)cf, 1.0f);
    const float gz = sel8f(r3, z0, z1, z2, z3, z4, z5, z6, z7) * inv;
    const float g1 = sel8f(r3, t0, t1, t2, t3, t4, t5, t6, t7) * inv;
    // z = relu(g1 + x@W1rRev + b1)
    const float xv = x[(long)i * H + lane];
    float s0 = 0.f, s1 = 0.f;
#pragma unroll
    for (int k = 0; k < H; k += 2) {
      s0 = fmaf(bcastf(xv, k),     (float)Wl[k * H + lane], s0);
      s1 = fmaf(bcastf(xv, k + 1), (float)Wl[(k + 1) * H + lane], s1);
    }
    const float z = fmaxf(g1 + bj + s0 + s1, 0.0f);
    // Y2fh = z@Wy2 ; PH = gz@Wt2 + z@Wp + bp
    float y0 = 0.f, y1 = 0.f, p0 = 0.f, p1 = 0.f;
#pragma unroll
    for (int k = 0; k < H; k += 2) {
      const float zk = bcastf(z, k),  zk1 = bcastf(z, k + 1);
      const float gk = bcastf(gz, k), gk1 = bcastf(gz, k + 1);
      y0 = fmaf(zk,  (float)Wl[4096 + k * H + lane], y0);
      y1 = fmaf(zk1, (float)Wl[4096 + (k + 1) * H + lane], y1);
      p0 = fmaf(gk,  (float)Wl[8192 + k * H + lane], p0);
      p0 = fmaf(zk,  (float)Wl[12288 + k * H + lane], p0);
      p1 = fmaf(gk1, (float)Wl[8192 + (k + 1) * H + lane], p1);
      p1 = fmaf(zk1, (float)Wl[12288 + (k + 1) * H + lane], p1);
    }
    y2_out[(long)i * H + lane] = (_Float16)(y0 + y1);
    ph_out[(long)i * H + lane] = (_Float16)(p0 + p1 + bp);
  }
}

// out[e] = sum_j relu(P[r,j] + Q[c,j] + db1[j]) * dW2[j] + db2
// Q lives in the interleaved ZT table (stride qs halves).
__global__ __launch_bounds__(256, 4) void edge_kernel(
    const int* __restrict__ row, const int* __restrict__ col,
    const _Float16* __restrict__ P, const _Float16* __restrict__ Q, int qs,
    const float* __restrict__ db1, const float* __restrict__ dW2,
    const float* __restrict__ db2, float* __restrict__ out)
{
  const int lane = threadIdx.x & 63;
  const int gw = (blockIdx.x * 256 + threadIdx.x) >> 6;
  const int nw = (gridDim.x * 256) >> 6;
  const int g = lane >> 4;
  const int sub = lane & 15;
  const f32x4 bj4 = *(const f32x4*)(db1 + 4 * sub);
  const f32x4 w24 = *(const f32x4*)(dW2 + 4 * sub);
  const float b2 = db2[0];
  for (int e = gw * 4; e < NL; e += nw * 4) {
    const int r0 = row[e], r1 = row[e + 1], r2i = row[e + 2], r3 = row[e + 3];
    const int c0 = col[e], c1 = col[e + 1], c2i = col[e + 2], c3 = col[e + 3];
    const int rs = sel4(g, r0, r1, r2i, r3);
    const int cs = sel4(g, c0, c1, c2i, c3);
    const f16x4 pv = *(const f16x4*)(P + (long)rs * H + sub * 4);
    const f16x4 qv = *(const f16x4*)(Q + (long)cs * qs + sub * 4);
    float h = fmaxf((float)pv[0] + (float)qv[0] + bj4[0], 0.f) * w24[0]
            + fmaxf((float)pv[1] + (float)qv[1] + bj4[1], 0.f) * w24[1]
            + fmaxf((float)pv[2] + (float)qv[2] + bj4[2], 0.f) * w24[2]
            + fmaxf((float)pv[3] + (float)qv[3] + bj4[3], 0.f) * w24[3];
    h += __shfl_xor(h, 1);
    h += __shfl_xor(h, 2);
    h += __shfl_xor(h, 4);
    h += __shfl_xor(h, 8);
    if (sub == 0) out[e + g] = h + b2;
  }
}

extern "C" void kernel_launch(void* const* d_in, const int* in_sizes, int n_in,
                              void* d_out, int out_size, void* d_ws, size_t ws_size,
                              hipStream_t stream) {
  const float* emb_loc = (const float*)d_in[0];
  const float* emb_exp = (const float*)d_in[1];
  const float* W1l_of  = (const float*)d_in[2];
  const float* b1_of   = (const float*)d_in[3];
  const float* W1r_of  = (const float*)d_in[4];
  const float* W1l_rev = (const float*)d_in[5];
  const float* b1_rev  = (const float*)d_in[6];
  const float* W1r_rev = (const float*)d_in[7];
  const float* W2l_of  = (const float*)d_in[8];
  const float* b2_of   = (const float*)d_in[9];
  const float* W2r_of  = (const float*)d_in[10];
  const float* W2l_rev = (const float*)d_in[11];
  const float* b2_rev  = (const float*)d_in[12];
  const float* W2r_rev = (const float*)d_in[13];
  const float* dW1     = (const float*)d_in[14];
  const float* db1     = (const float*)d_in[15];
  const float* dW2     = (const float*)d_in[16];
  const float* db2     = (const float*)d_in[17];
  const int*   edge_of = (const int*)d_in[18];
  const int*   eli     = (const int*)d_in[20];

  const int* src = edge_of;
  const int* dst = edge_of + NE;
  const int* row = eli;
  const int* col = eli + NL;

  if (ws_size < WS_NEED) return;

  char* ws = (char*)d_ws;
  int*            cnt_loc = (int*)(ws);
  int*            cnt_exp = (int*)(ws + 80000);
  int*            nbr_loc = (int*)(ws + 880064);
  unsigned short* nbr_exp = (unsigned short*)(ws + 11120064);
  _Float16*       Ylh     = (_Float16*)(ws + 23920064);
  _Float16*       Y2fh    = (_Float16*)(ws + 26480064);
  _Float16*       PH      = (_Float16*)(ws + 34160064);
  _Float16*       W1rT16  = (_Float16*)(ws + 36720064);
  _Float16*       W1lrT16 = (_Float16*)(ws + 36728256);
  _Float16*       WfqT16  = (_Float16*)(ws + 36736448);
  _Float16*       W1rRevH16 = (_Float16*)(ws + 36752832);
  _Float16*       Wt2H16  = (_Float16*)(ws + 36761024);
  _Float16*       WpH16   = (_Float16*)(ws + 36769216);
  _Float16*       Wy2H16  = (_Float16*)(ws + 36777472);
  _Float16*       ZT      = (_Float16*)(ws + 39280064);   // 200000 x 256B
  u32*            expQ    = (u32*)(ws + 64880064);
  u32*            locQ    = (u32*)(ws + 72220096);
  int*            qcnt    = (int*)(ws + 79551936);
  int*            flbk    = (int*)(ws + 79553552);
  u64*            flbkQ   = (u64*)(ws + 79554048);
  float*          Wf_q    = (float*)(ws + 90480064);
  float*          Wf_y2   = (float*)(ws + 90496448);
  float*          Wf_t2   = (float*)(ws + 90512832);
  float*          Wf_p    = (float*)(ws + 90529216);
  float*          bf_q    = (float*)(ws + 90545600);
  float*          bf_p    = (float*)(ws + 90545856);
  float*          out     = (float*)d_out;

  (void)hipMemsetAsync(ws + 79551936, 0, 2048, stream);

  // ---- CSR fill (loc rows sorted by expert id) ----
  bin_kernel<<<NBIN, 256, 0, stream>>>(src, dst, expQ, locQ, qcnt, flbk, flbkQ);
  build_kernel<<<NBE + NBL, 256, 0, stream>>>(expQ, locQ, qcnt,
      nbr_exp, nbr_loc, cnt_exp, cnt_loc);
  prep_kernel<<<1259, 256, 0, stream>>>(W2r_of, W2l_of, W2l_rev, W2r_rev,
                                        dW1, b2_of, b2_rev,
                                        Wf_q, Wf_y2, Wf_t2, Wf_p, bf_q, bf_p,
                                        flbk, flbkQ, nbr_exp, nbr_loc,
                                        cnt_exp, cnt_loc,
                                        emb_loc, Ylh, W1l_of,
                                        W1r_of, W1l_rev, W1r_rev,
                                        W1rT16, W1lrT16, WfqT16,
                                        W1rRevH16, Wt2H16, WpH16, Wy2H16);

  // passA: ZT[:,0:64] = relu(emb_exp@W1r_of + gatherE(Ylh) + b1_of)  (ZE)
  //        ZT[:,64:128] = emb_exp@W1l_rev                            (TH)
  mfma_pass_kernel<<<NEXP / 16, 256, 0, stream>>>(nbr_exp, cnt_exp, Ylh,
      emb_exp, (const _Float16*)nullptr, 0, ZT, 128, W1rT16, b1_of, 1,
      ZT + 64, 128, W1lrT16);
  // fused loc: z (internal) + Y2fh + PH in one sorted dual-half gather
  loc_fused_kernel<<<1250, 256, 0, stream>>>(nbr_loc, cnt_loc, ZT,
      emb_loc, Y2fh, PH, W1rRevH16, Wy2H16, Wt2H16, WpH16, b1_rev, bf_p);
  // passB: Qh = ZE@Wf_q + gatherE(Y2fh) + bf_q  (in-place over ZT ZE-half)
  mfma_pass_kernel<<<NEXP / 16, 256, 0, stream>>>(nbr_exp, cnt_exp, Y2fh,
      (const float*)nullptr, ZT, 128, ZT, 128, WfqT16, bf_q, 0,
      (_Float16*)nullptr, 0, (const _Float16*)nullptr);
  // edge decode (Q = Qh half of ZT, stride 128)
  edge_kernel<<<2048, 256, 0, stream>>>(row, col, PH, ZT, 128,
                                        db1, dW2, db2, out);
}

// Round 11
// 640.605 us; speedup vs baseline: 1.5607x; 1.5607x over previous
//
#include <hip/hip_runtime.h>

#define H 64
#define NE 1500000
#define NLOC 20000
#define NEXP 200000
#define NL 400000
#define PAD_E 32
#define PAD_L 128

// ---- bucket-sort fill geometry ----
#define EB 896
#define NBE 224
#define LB 112
#define NBL 179
#define BIN_CHUNK 2048
#define NBIN ((NE + BIN_CHUNK - 1) / BIN_CHUNK)   // 733
#define EBSLOT 28
#define LBSLOT 32
#define ECAP 8192
#define LCAP 10240
#define FCAP 4096

// ---- workspace layout (bytes) ----  (r6 layout)
// cnt_loc [0,80000)  cnt_exp [80000,880000)
// nbr_loc [880064,11120064)  nbr_exp(u16) [11120064,23920064)
// Ylh(f16)  [23920064,26480064)   Y2fh(f16) [26480064,29040064)
// z_loc(f32)[29040064,34160064)   PH(f16)   [34160064,36720064)
// weights hole: W1rT16 [36720064,+8192) W1lrT16 [36728256,+8192)
//   WfqT16 [36736448,+8192) Wt2H16 [36761024,+8192) WpH16 [36769216,+8192)
// ZE(f16)   [39280064,64880064)   z_exph -> Qh (in-place)
// TH(f16)   [64880064,90480064)   T1h
//   (aliased pre-passA: expQ/locQ/qcnt/flbk/flbkQ)
// Wf_q [90480064) Wf_y2 [90496448) Wf_t2 [90512832) Wf_p [90529216)
// bf_q [90545600) bf_p [90545856)
#define WS_NEED 90546112ULL

typedef int vint4 __attribute__((ext_vector_type(4)));
typedef _Float16 f16x8 __attribute__((ext_vector_type(8)));
typedef _Float16 f16x4 __attribute__((ext_vector_type(4)));
typedef float f32x4 __attribute__((ext_vector_type(4)));
typedef unsigned int u32;
typedef unsigned short u16;
typedef unsigned long long u64;

__device__ __forceinline__ float bcastf(float v, int k) {
  return __int_as_float(__builtin_amdgcn_readlane(__float_as_int(v), k));
}
__device__ __forceinline__ int bcasti(int v, int k) {
  return __builtin_amdgcn_readlane(v, k);
}
__device__ __forceinline__ int sel4(int g, int n0, int n1, int n2, int n3) {
  return (g & 2) ? ((g & 1) ? n3 : n2) : ((g & 1) ? n1 : n0);
}

// ---------------- bucket-sort fill, pass 1: bin edges ----------------
__global__ __launch_bounds__(256) void bin_kernel(
    const int* __restrict__ src, const int* __restrict__ dst,
    u32* __restrict__ expQ, u32* __restrict__ locQ,
    int* __restrict__ qcnt, int* __restrict__ flbk_cnt,
    u64* __restrict__ flbkQ)
{
  __shared__ u32 eb[NBE * EBSLOT];
  __shared__ u32 lb[NBL * LBSLOT];
  __shared__ int ec[NBE], lc[NBL], ebase[NBE], lbase[NBL];

  const int tid = threadIdx.x;
  for (int i = tid; i < NBE; i += 256) ec[i] = 0;
  for (int i = tid; i < NBL; i += 256) lc[i] = 0;
  __syncthreads();

  const long base = (long)blockIdx.x * BIN_CHUNK + tid * 8;
  if (base < NE) {
    vint4 s0 = __builtin_nontemporal_load((const vint4*)(src + base));
    vint4 s1 = __builtin_nontemporal_load((const vint4*)(src + base + 4));
    vint4 d0 = __builtin_nontemporal_load((const vint4*)(dst + base));
    vint4 d1 = __builtin_nontemporal_load((const vint4*)(dst + base + 4));
    int ss[8] = {s0.x, s0.y, s0.z, s0.w, s1.x, s1.y, s1.z, s1.w};
    int dd[8] = {d0.x, d0.y, d0.z, d0.w, d1.x, d1.y, d1.z, d1.w};
#pragma unroll
    for (int k = 0; k < 8; k++) {
      const u32 d = (u32)dd[k], s = (u32)ss[k];
      {
        const u32 b = d / (u32)EB;
        const int pos = atomicAdd(&ec[b], 1);
        if (pos < EBSLOT) {
          eb[b * EBSLOT + pos] = ((d - b * EB) << 16) | s;
        } else {
          int fi = atomicAdd(flbk_cnt, 1);
          if (fi < FCAP) flbkQ[fi] = ((u64)d << 32) | (u64)s;
        }
      }
      {
        const u32 b = s / (u32)LB;
        const int pos = atomicAdd(&lc[b], 1);
        if (pos < LBSLOT) {
          lb[b * LBSLOT + pos] = ((s - b * LB) << 18) | d;
        } else {
          int fi = atomicAdd(flbk_cnt, 1);
          if (fi < FCAP) flbkQ[fi] = (1ULL << 63) | ((u64)s << 32) | (u64)d;
        }
      }
    }
  }
  __syncthreads();

  for (int i = tid; i < NBE; i += 256) {
    const int c = min(ec[i], EBSLOT);
    ebase[i] = c ? atomicAdd(&qcnt[i], c) : 0;
  }
  for (int i = tid; i < NBL; i += 256) {
    const int c = min(lc[i], LBSLOT);
    lbase[i] = c ? atomicAdd(&qcnt[NBE + i], c) : 0;
  }
  __syncthreads();

  const int wid = tid >> 6, ln = tid & 63;
  for (int b = wid; b < NBE; b += 4) {
    const int c = min(ec[b], EBSLOT);
    if (ln < c) {
      const int idx = ebase[b] + ln;
      const u32 r = eb[b * EBSLOT + ln];
      if (idx < ECAP) {
        expQ[(long)b * ECAP + idx] = r;
      } else {
        int fi = atomicAdd(flbk_cnt, 1);
        if (fi < FCAP)
          flbkQ[fi] = ((u64)(b * EB + (r >> 16)) << 32) | (u64)(r & 0xFFFF);
      }
    }
  }
  for (int b = wid; b < NBL; b += 4) {
    const int c = min(lc[b], LBSLOT);
    if (ln < c) {
      const int idx = lbase[b] + ln;
      const u32 r = lb[b * LBSLOT + ln];
      if (idx < LCAP) {
        locQ[(long)b * LCAP + idx] = r;
      } else {
        int fi = atomicAdd(flbk_cnt, 1);
        if (fi < FCAP)
          flbkQ[fi] = (1ULL << 63) | ((u64)(b * LB + (r >> 18)) << 32) |
                      (u64)(r & 0x3FFFF);
      }
    }
  }
}

// ---------------- bucket-sort fill, pass 2: build padded CSR ----------------
// r11: loc rows SORTED by expert id (bitonic min/max network -> permutation;
// mean is order-invariant, so correctness unaffected — only locality).
// Sequential walk over a sorted list = implicit quantile alignment across
// waves (at step k all waves sit near quantile k/deg of the expert table).
__global__ __launch_bounds__(256) void build_kernel(
    const u32* __restrict__ expQ, const u32* __restrict__ locQ,
    const int* __restrict__ qcnt,
    u16* __restrict__ nbr_exp, int* __restrict__ nbr_loc,
    int* __restrict__ cnt_exp, int* __restrict__ cnt_loc)
{
  __shared__ char ldsraw[60928];
  const int tid = threadIdx.x;
  if (blockIdx.x < NBE) {
    const int b = blockIdx.x;
    u16* rows = (u16*)ldsraw;
    int* cnts = (int*)(ldsraw + 57344);
    for (int i = tid; i < EB; i += 256) cnts[i] = 0;
    __syncthreads();
    const int n = min(qcnt[b], ECAP);
    for (int i = tid; i < n; i += 256) {
      const u32 r = expQ[(long)b * ECAP + i];
      const int nl = (int)(r >> 16);
      const int pos = atomicAdd(&cnts[nl], 1);
      if (pos < PAD_E) rows[nl * PAD_E + pos] = (u16)(r & 0xFFFF);
    }
    __syncthreads();
    const int node0 = b * EB;
    const int nn = min(EB, NEXP - node0);
    u32* grows = (u32*)(nbr_exp + (long)node0 * PAD_E);
    const u32* lrows = (const u32*)rows;
    for (int j = tid; j < nn * (PAD_E / 2); j += 256) grows[j] = lrows[j];
    for (int i = tid; i < nn; i += 256) cnt_exp[node0 + i] = cnts[i];
  } else {
    const int b = blockIdx.x - NBE;
    int* rows = (int*)ldsraw;
    int* cnts = (int*)(ldsraw + 57344);
    for (int i = tid; i < LB; i += 256) cnts[i] = 0;
    for (int i = tid; i < LB * PAD_L; i += 256) rows[i] = 0x3FFFF;  // pad
    __syncthreads();
    const int n = min(qcnt[NBE + b], LCAP);
    for (int i = tid; i < n; i += 256) {
      const u32 r = locQ[(long)b * LCAP + i];
      const int sl = (int)(r >> 18);
      const int pos = atomicAdd(&cnts[sl], 1);
      if (pos < PAD_L) rows[sl * PAD_L + pos] = (int)(r & 0x3FFFF);
    }
    __syncthreads();
    const int ln = tid & 63, wd = tid >> 6;
    for (int r = wd; r < LB; r += 4) {
      int* row = rows + r * PAD_L;
      int v0 = row[ln], v1 = row[64 + ln];
      for (int k = 2; k <= 128; k <<= 1) {
        for (int j = k >> 1; j >= 1; j >>= 1) {
          if (j == 64) {
            const int a = min(v0, v1), bmx = max(v0, v1);
            v0 = a; v1 = bmx;
          } else {
            const int p0 = __shfl_xor(v0, j);
            const int p1 = __shfl_xor(v1, j);
            const bool up = ((ln & j) == 0);
            const bool a0 = ((ln & k) == 0);
            const bool a1 = (((ln + 64) & k) == 0);
            v0 = (up == a0) ? min(v0, p0) : max(v0, p0);
            v1 = (up == a1) ? min(v1, p1) : max(v1, p1);
          }
        }
      }
      row[ln] = v0; row[64 + ln] = v1;
    }
    __syncthreads();
    const int node0 = b * LB;
    const int nn = min(LB, NLOC - node0);
    int* grows = nbr_loc + (long)node0 * PAD_L;
    for (int j = tid; j < nn * PAD_L; j += 256) grows[j] = rows[j];
    for (int i = tid; i < nn; i += 256) cnt_loc[node0 + i] = cnts[i];
  }
}

// prep_kernel: folds + f16 weight copies + fallback drain + dense Ylh.
__global__ __launch_bounds__(256) void prep_kernel(
    const float* __restrict__ W2r_of, const float* __restrict__ W2l_of,
    const float* __restrict__ W2l_rev, const float* __restrict__ W2r_rev,
    const float* __restrict__ dW1, const float* __restrict__ b2_of,
    const float* __restrict__ b2_rev,
    float* __restrict__ Wf_q, float* __restrict__ Wf_y2,
    float* __restrict__ Wf_t2, float* __restrict__ Wf_p,
    float* __restrict__ bf_q, float* __restrict__ bf_p,
    const int* __restrict__ flbk_cnt, const u64* __restrict__ flbkQ,
    u16* __restrict__ nbr_exp, int* __restrict__ nbr_loc,
    int* __restrict__ cnt_exp, int* __restrict__ cnt_loc,
    const float* __restrict__ emb_loc, _Float16* __restrict__ Ylh,
    const float* __restrict__ W1l_of,
    const float* __restrict__ W1r_of, const float* __restrict__ W1l_rev,
    _Float16* __restrict__ W1rT16, _Float16* __restrict__ W1lrT16,
    _Float16* __restrict__ WfqT16,
    _Float16* __restrict__ Wt2H16, _Float16* __restrict__ WpH16)
{
  const int lane = threadIdx.x & 63;
  const int w = threadIdx.x >> 6;
  const float* dW1a = dW1;
  const float* dW1b = dW1 + H * H;
  if (blockIdx.x < 4) {
    const float* A; const float* B; float* C;
    _Float16* CT; _Float16* CH;
    switch (blockIdx.x) {
      case 0:  A = W2r_of;  B = dW1b; C = Wf_q;  CT = WfqT16; CH = nullptr; break;
      case 1:  A = W2l_of;  B = dW1b; C = Wf_y2; CT = nullptr; CH = nullptr; break;
      case 2:  A = W2l_rev; B = dW1a; C = Wf_t2; CT = nullptr; CH = Wt2H16; break;
      default: A = W2r_rev; B = dW1a; C = Wf_p;  CT = nullptr; CH = WpH16;  break;
    }
    float b[H];
#pragma unroll
    for (int k = 0; k < H; k++) b[k] = B[k * H + lane];
    for (int r = w * 16; r < w * 16 + 16; r++) {
      const float xv = A[r * H + lane];
      float a0 = 0.f, a1 = 0.f;
#pragma unroll
      for (int k = 0; k < H; k += 2) {
        a0 += bcastf(xv, k)     * b[k];
        a1 += bcastf(xv, k + 1) * b[k + 1];
      }
      const float val = a0 + a1;
      C[r * H + lane] = val;
      if (CT) CT[(long)lane * H + r] = (_Float16)val;   // transposed f16
      if (CH) CH[(long)r * H + lane] = (_Float16)val;   // row-major f16
    }
  } else if (blockIdx.x == 4) {
    if (w < 2) {
      const float* bv_src = (w == 0) ? b2_of : b2_rev;
      const float* B      = (w == 0) ? dW1b  : dW1a;
      float* o            = (w == 0) ? bf_q  : bf_p;
      float wk[H];
#pragma unroll
      for (int k = 0; k < H; k++) wk[k] = B[k * H + lane];
      const float bv = bv_src[lane];
      float a = 0.f;
#pragma unroll
      for (int k = 0; k < H; k++) a += bcastf(bv, k) * wk[k];
      o[lane] = a;
    }
  } else if (blockIdx.x == 5) {
    const int n = min(*flbk_cnt, FCAP);
    for (int i = threadIdx.x; i < n; i += 256) {
      const u64 rec = flbkQ[i];
      const int node = (int)((rec >> 32) & 0x3FFFF);
      const int val  = (int)(rec & 0x3FFFF);
      if ((rec >> 63) == 0) {
        int pos = atomicAdd(&cnt_exp[node], 1);
        if (pos < PAD_E) nbr_exp[(long)node * PAD_E + pos] = (u16)val;
      } else {
        int pos = atomicAdd(&cnt_loc[node], 1);
        if (pos < PAD_L) nbr_loc[(long)node * PAD_L + pos] = val;
      }
    }
  } else if (blockIdx.x < 8) {
    // f16 transposes for MFMA B-fragments
    const float* S = (blockIdx.x == 6) ? W1r_of : W1l_rev;
    _Float16* D    = (blockIdx.x == 6) ? W1rT16 : W1lrT16;
    for (int k = w * 16; k < w * 16 + 16; k++)
      D[(long)lane * H + k] = (_Float16)S[(long)k * H + lane];
  } else {
    // dense: Ylh = emb_loc @ W1l_of (fp16 out), grid-stride 4 rows/wave
    float wreg[H];
#pragma unroll
    for (int k = 0; k < H; k++) wreg[k] = W1l_of[k * H + lane];
    const int gw2 = (blockIdx.x - 8) * 4 + w;       // 0..4999
    for (int r = gw2; r < NLOC; r += 5000) {
      const float xv = emb_loc[(long)r * H + lane];
      float a0 = 0.f, a1 = 0.f;
#pragma unroll
      for (int k = 0; k < H; k += 2) {
        a0 += bcastf(xv, k)     * wreg[k];
        a1 += bcastf(xv, k + 1) * wreg[k + 1];
      }
      Ylh[(long)r * H + lane] = (_Float16)(a0 + a1);
    }
  }
}

// out16 = x @ W (no bias); fp32 in, fp16 out.
__global__ __launch_bounds__(256, 4) void dense_linear_kernel(
    const float* __restrict__ x, _Float16* __restrict__ out16,
    const float* __restrict__ W, int n)
{
  const int lane = threadIdx.x & 63;
  const int gw = (blockIdx.x * 256 + threadIdx.x) >> 6;
  const int nw = (gridDim.x * 256) >> 6;
  float w[H];
#pragma unroll
  for (int k = 0; k < H; k++) w[k] = W[k * H + lane];
  for (int i = gw; i < n; i += nw) {
    const float xv = x[i * H + lane];
    float a0 = 0.f, a1 = 0.f;
#pragma unroll
    for (int k = 0; k < H; k += 2) {
      a0 += bcastf(xv, k)     * w[k];
      a1 += bcastf(xv, k + 1) * w[k + 1];
    }
    out16[i * H + lane] = (_Float16)(a0 + a1);
  }
}

// Exp-side MFMA pass (dual-B optional, gather/bias/relu optional). r6 form.
__global__ __launch_bounds__(256, 4) void mfma_pass_kernel(
    const u16* __restrict__ nbr, const int* __restrict__ cnt,
    const _Float16* __restrict__ y,
    const float* a32, const _Float16* a16,
    _Float16* out1, const _Float16* __restrict__ W1T,
    const float* __restrict__ bias, int relu,
    _Float16* out2, const _Float16* __restrict__ W2T)
{
  const int w = threadIdx.x >> 6;
  const int lane = threadIdx.x & 63;
  const int q = lane >> 4;
  const int cidx = lane & 15;
  const int rb = blockIdx.x * 16;

  __shared__ float Gs[16 * 68];

  const _Float16* bt1 = W1T + (long)(w * 16 + cidx) * H;
  f16x8 b1lo = *(const f16x8*)(bt1 + q * 8);
  f16x8 b1hi = *(const f16x8*)(bt1 + 32 + q * 8);
  f16x8 b2lo, b2hi;
  if (out2) {
    const _Float16* bt2 = W2T + (long)(w * 16 + cidx) * H;
    b2lo = *(const f16x8*)(bt2 + q * 8);
    b2hi = *(const f16x8*)(bt2 + 32 + q * 8);
  }

  f16x8 a0, a1;
  if (a16) {
    const _Float16* ar = a16 + (long)(rb + cidx) * H;
    a0 = *(const f16x8*)(ar + q * 8);
    a1 = *(const f16x8*)(ar + 32 + q * 8);
  } else {
    const float* ar = a32 + (long)(rb + cidx) * H;
    f32x4 v0 = *(const f32x4*)(ar + q * 8);
    f32x4 v1 = *(const f32x4*)(ar + q * 8 + 4);
    f32x4 v2 = *(const f32x4*)(ar + 32 + q * 8);
    f32x4 v3 = *(const f32x4*)(ar + 32 + q * 8 + 4);
#pragma unroll
    for (int j = 0; j < 4; j++) {
      a0[j] = (_Float16)v0[j];
      a0[j + 4] = (_Float16)v1[j];
      a1[j] = (_Float16)v2[j];
      a1[j + 4] = (_Float16)v3[j];
    }
  }

  if (y) {
    const int i0r = rb + w * 4;
    const int g = lane >> 4;
    const int sub = lane & 15;
    int c4v[4];
#pragma unroll
    for (int rr = 0; rr < 4; rr++) c4v[rr] = cnt[i0r + rr];
    int id4[4];
#pragma unroll
    for (int rr = 0; rr < 4; rr++) {
      const int c = min(c4v[rr], PAD_E);
      id4[rr] = (lane < c) ? (int)nbr[(long)(i0r + rr) * PAD_E + lane] : 0;
    }
#pragma unroll
    for (int rr = 0; rr < 4; rr++) {
      const int cc = min(c4v[rr], PAD_E);
      const int id = id4[rr];
      const int kl = cc - 1;
      float s0 = 0.f, s1 = 0.f, s2 = 0.f, s3 = 0.f;
      for (int k = 0; k < cc; k += 4) {
        const int n0 = bcasti(id, k);
        const int n1 = bcasti(id, min(k + 1, kl));
        const int n2 = bcasti(id, min(k + 2, kl));
        const int n3 = bcasti(id, min(k + 3, kl));
        const int ns = sel4(g, n0, n1, n2, n3);
        const f16x4 v = *(const f16x4*)(y + (long)ns * H + sub * 4);
        const float msk = (k + g < cc) ? 1.0f : 0.0f;
        s0 = fmaf(msk, (float)v[0], s0);
        s1 = fmaf(msk, (float)v[1], s1);
        s2 = fmaf(msk, (float)v[2], s2);
        s3 = fmaf(msk, (float)v[3], s3);
      }
      s0 += __shfl_xor(s0, 16); s0 += __shfl_xor(s0, 32);
      s1 += __shfl_xor(s1, 16); s1 += __shfl_xor(s1, 32);
      s2 += __shfl_xor(s2, 16); s2 += __shfl_xor(s2, 32);
      s3 += __shfl_xor(s3, 16); s3 += __shfl_xor(s3, 32);
      const float inv = 1.0f / fmaxf((float)c4v[rr], 1.0f);
      if (lane < 16) {
        float* gp = &Gs[(w * 4 + rr) * 68 + 4 * lane];
        gp[0] = s0 * inv; gp[1] = s1 * inv;
        gp[2] = s2 * inv; gp[3] = s3 * inv;
      }
    }
  }

  f32x4 acc1 = {0.f, 0.f, 0.f, 0.f};
  acc1 = __builtin_amdgcn_mfma_f32_16x16x32_f16(a0, b1lo, acc1, 0, 0, 0);
  acc1 = __builtin_amdgcn_mfma_f32_16x16x32_f16(a1, b1hi, acc1, 0, 0, 0);
  f32x4 acc2 = {0.f, 0.f, 0.f, 0.f};
  if (out2) {
    acc2 = __builtin_amdgcn_mfma_f32_16x16x32_f16(a0, b2lo, acc2, 0, 0, 0);
    acc2 = __builtin_amdgcn_mfma_f32_16x16x32_f16(a1, b2hi, acc2, 0, 0, 0);
  }

  const float bj = bias ? bias[w * 16 + cidx] : 0.f;
  __syncthreads();
#pragma unroll
  for (int reg = 0; reg < 4; reg++) {
    const int r = q * 4 + reg;
    float v = acc1[reg] + bj;
    if (y) v += Gs[r * 68 + w * 16 + cidx];
    if (relu) v = fmaxf(v, 0.f);
    out1[(long)(rb + r) * H + w * 16 + cidx] = (_Float16)v;
    if (out2)
      out2[(long)(rb + r) * H + w * 16 + cidx] = (_Float16)acc2[reg];
  }
}

// loc pass 1 (r6's proven loop): z = relu(mean-gather(T) + x@Wr + b).
// Sorted lists make the sequential walk an implicit quantile sweep.
__global__ __launch_bounds__(256, 4) void loc_gather_kernel(
    const int* __restrict__ nbr, const int* __restrict__ cnt,
    const _Float16* __restrict__ T, const float* __restrict__ x,
    float* __restrict__ out32,
    const float* __restrict__ Wr, const float* __restrict__ bias,
    int n, int relu)
{
  const int lane = threadIdx.x & 63;
  const int gw = (blockIdx.x * 256 + threadIdx.x) >> 6;
  const int nw = (gridDim.x * 256) >> 6;
  float wr[H];
#pragma unroll
  for (int k = 0; k < H; k++) wr[k] = Wr[k * H + lane];
  const float bj = bias[lane];
  for (int i = gw; i < n; i += nw) {
    const int c = cnt[i];
    const int cc = min(c, PAD_L);
    const int* nb = nbr + (long)i * PAD_L;
    float s0 = 0.f, s1 = 0.f, s2 = 0.f, s3 = 0.f;
    float s4 = 0.f, s5 = 0.f, s6 = 0.f, s7 = 0.f;
    int e = 0;
    while (e < cc) {
      const int m = min(cc - e, 64);
      const int id = (lane < m) ? nb[e + lane] : 0;
      int k = 0;
      const int m8 = m & ~7;
      for (; k < m8; k += 8) {
        const int i0 = bcasti(id, k),     i1 = bcasti(id, k + 1),
                  i2 = bcasti(id, k + 2), i3 = bcasti(id, k + 3),
                  i4 = bcasti(id, k + 4), i5 = bcasti(id, k + 5),
                  i6 = bcasti(id, k + 6), i7 = bcasti(id, k + 7);
        s0 += (float)T[(long)i0 * H + lane];
        s1 += (float)T[(long)i1 * H + lane];
        s2 += (float)T[(long)i2 * H + lane];
        s3 += (float)T[(long)i3 * H + lane];
        s4 += (float)T[(long)i4 * H + lane];
        s5 += (float)T[(long)i5 * H + lane];
        s6 += (float)T[(long)i6 * H + lane];
        s7 += (float)T[(long)i7 * H + lane];
      }
      const int m4 = m & ~3;
      for (; k < m4; k += 4) {
        const int i0 = bcasti(id, k), i1 = bcasti(id, k + 1),
                  i2 = bcasti(id, k + 2), i3 = bcasti(id, k + 3);
        s0 += (float)T[(long)i0 * H + lane];
        s1 += (float)T[(long)i1 * H + lane];
        s2 += (float)T[(long)i2 * H + lane];
        s3 += (float)T[(long)i3 * H + lane];
      }
      for (; k < m; k++) s0 += (float)T[(long)bcasti(id, k) * H + lane];
      e += m;
    }
    const float agg = (((s0 + s1) + (s2 + s3)) + ((s4 + s5) + (s6 + s7))) /
                      fmaxf((float)c, 1.0f);
    const float xv = x[(long)i * H + lane];
    float a0 = 0.f, a1 = 0.f;
#pragma unroll
    for (int k = 0; k < H; k += 2) {
      a0 += bcastf(xv, k)     * wr[k];
      a1 += bcastf(xv, k + 1) * wr[k + 1];
    }
    float acc = agg + bj + a0 + a1;
    if (relu) acc = fmaxf(acc, 0.0f);
    out32[(long)i * H + lane] = acc;
  }
}

// loc pass 2 (fold applied, validated r7): PH = mean-gather(ZE)@Wt2 +
// z_loc@Wp + bf_p. Same proven gather loop; Wt2/Wp staged f16 in LDS.
__global__ __launch_bounds__(256, 4) void loc_ph_kernel(
    const int* __restrict__ nbr, const int* __restrict__ cnt,
    const _Float16* __restrict__ ZEt, const float* __restrict__ z_loc,
    _Float16* __restrict__ ph_out,
    const _Float16* __restrict__ Wt216, const _Float16* __restrict__ Wp16,
    const float* __restrict__ bfp)
{
  __shared__ _Float16 Wl[2 * 4096];   // 16KB
  const int tid = threadIdx.x;
  for (int j = tid * 8; j < 4096; j += 2048) {
    *(f16x8*)&Wl[j]        = *(const f16x8*)&Wt216[j];
    *(f16x8*)&Wl[4096 + j] = *(const f16x8*)&Wp16[j];
  }
  __syncthreads();

  const int lane = tid & 63;
  const int gw = (blockIdx.x * 256 + tid) >> 6;
  const int nw = (gridDim.x * 256) >> 6;
  const float bp = bfp[lane];
  for (int i = gw; i < NLOC; i += nw) {
    const int c = cnt[i];
    const int cc = min(c, PAD_L);
    const int* nb = nbr + (long)i * PAD_L;
    float s0 = 0.f, s1 = 0.f, s2 = 0.f, s3 = 0.f;
    float s4 = 0.f, s5 = 0.f, s6 = 0.f, s7 = 0.f;
    int e = 0;
    while (e < cc) {
      const int m = min(cc - e, 64);
      const int id = (lane < m) ? nb[e + lane] : 0;
      int k = 0;
      const int m8 = m & ~7;
      for (; k < m8; k += 8) {
        const int i0 = bcasti(id, k),     i1 = bcasti(id, k + 1),
                  i2 = bcasti(id, k + 2), i3 = bcasti(id, k + 3),
                  i4 = bcasti(id, k + 4), i5 = bcasti(id, k + 5),
                  i6 = bcasti(id, k + 6), i7 = bcasti(id, k + 7);
        s0 += (float)ZEt[(long)i0 * H + lane];
        s1 += (float)ZEt[(long)i1 * H + lane];
        s2 += (float)ZEt[(long)i2 * H + lane];
        s3 += (float)ZEt[(long)i3 * H + lane];
        s4 += (float)ZEt[(long)i4 * H + lane];
        s5 += (float)ZEt[(long)i5 * H + lane];
        s6 += (float)ZEt[(long)i6 * H + lane];
        s7 += (float)ZEt[(long)i7 * H + lane];
      }
      const int m4 = m & ~3;
      for (; k < m4; k += 4) {
        const int i0 = bcasti(id, k), i1 = bcasti(id, k + 1),
                  i2 = bcasti(id, k + 2), i3 = bcasti(id, k + 3);
        s0 += (float)ZEt[(long)i0 * H + lane];
        s1 += (float)ZEt[(long)i1 * H + lane];
        s2 += (float)ZEt[(long)i2 * H + lane];
        s3 += (float)ZEt[(long)i3 * H + lane];
      }
      for (; k < m; k++) s0 += (float)ZEt[(long)bcasti(id, k) * H + lane];
      e += m;
    }
    const float gz = (((s0 + s1) + (s2 + s3)) + ((s4 + s5) + (s6 + s7))) /
                     fmaxf((float)c, 1.0f);
    const float zv = z_loc[(long)i * H + lane];
    float p0 = 0.f, p1 = 0.f;
#pragma unroll
    for (int k = 0; k < H; k += 2) {
      p0 = fmaf(bcastf(gz, k),     (float)Wl[k * H + lane], p0);
      p0 = fmaf(bcastf(zv, k),     (float)Wl[4096 + k * H + lane], p0);
      p1 = fmaf(bcastf(gz, k + 1), (float)Wl[(k + 1) * H + lane], p1);
      p1 = fmaf(bcastf(zv, k + 1), (float)Wl[4096 + (k + 1) * H + lane], p1);
    }
    ph_out[(long)i * H + lane] = (_Float16)(p0 + p1 + bp);
  }
}

// out[e] = sum_j relu(P[r,j] + Q[c,j] + db1[j]) * dW2[j] + db2  (P,Q fp16)
__global__ __launch_bounds__(256, 4) void edge_kernel(
    const int* __restrict__ row, const int* __restrict__ col,
    const _Float16* __restrict__ P, const _Float16* __restrict__ Q,
    const float* __restrict__ db1, const float* __restrict__ dW2,
    const float* __restrict__ db2, float* __restrict__ out)
{
  const int lane = threadIdx.x & 63;
  const int gw = (blockIdx.x * 256 + threadIdx.x) >> 6;
  const int nw = (gridDim.x * 256) >> 6;
  const int g = lane >> 4;
  const int sub = lane & 15;
  const f32x4 bj4 = *(const f32x4*)(db1 + 4 * sub);
  const f32x4 w24 = *(const f32x4*)(dW2 + 4 * sub);
  const float b2 = db2[0];
  for (int e = gw * 4; e < NL; e += nw * 4) {
    const int r0 = row[e], r1 = row[e + 1], r2i = row[e + 2], r3 = row[e + 3];
    const int c0 = col[e], c1 = col[e + 1], c2i = col[e + 2], c3 = col[e + 3];
    const int rs = sel4(g, r0, r1, r2i, r3);
    const int cs = sel4(g, c0, c1, c2i, c3);
    const f16x4 pv = *(const f16x4*)(P + (long)rs * H + sub * 4);
    const f16x4 qv = *(const f16x4*)(Q + (long)cs * H + sub * 4);
    float h = fmaxf((float)pv[0] + (float)qv[0] + bj4[0], 0.f) * w24[0]
            + fmaxf((float)pv[1] + (float)qv[1] + bj4[1], 0.f) * w24[1]
            + fmaxf((float)pv[2] + (float)qv[2] + bj4[2], 0.f) * w24[2]
            + fmaxf((float)pv[3] + (float)qv[3] + bj4[3], 0.f) * w24[3];
    h += __shfl_xor(h, 1);
    h += __shfl_xor(h, 2);
    h += __shfl_xor(h, 4);
    h += __shfl_xor(h, 8);
    if (sub == 0) out[e + g] = h + b2;
  }
}

extern "C" void kernel_launch(void* const* d_in, const int* in_sizes, int n_in,
                              void* d_out, int out_size, void* d_ws, size_t ws_size,
                              hipStream_t stream) {
  const float* emb_loc = (const float*)d_in[0];
  const float* emb_exp = (const float*)d_in[1];
  const float* W1l_of  = (const float*)d_in[2];
  const float* b1_of   = (const float*)d_in[3];
  const float* W1r_of  = (const float*)d_in[4];
  const float* W1l_rev = (const float*)d_in[5];
  const float* b1_rev  = (const float*)d_in[6];
  const float* W1r_rev = (const float*)d_in[7];
  const float* W2l_of  = (const float*)d_in[8];
  const float* b2_of   = (const float*)d_in[9];
  const float* W2r_of  = (const float*)d_in[10];
  const float* W2l_rev = (const float*)d_in[11];
  const float* b2_rev  = (const float*)d_in[12];
  const float* W2r_rev = (const float*)d_in[13];
  const float* dW1     = (const float*)d_in[14];
  const float* db1     = (const float*)d_in[15];
  const float* dW2     = (const float*)d_in[16];
  const float* db2     = (const float*)d_in[17];
  const int*   edge_of = (const int*)d_in[18];
  const int*   eli     = (const int*)d_in[20];

  const int* src = edge_of;
  const int* dst = edge_of + NE;
  const int* row = eli;
  const int* col = eli + NL;

  if (ws_size < WS_NEED) return;

  char* ws = (char*)d_ws;
  int*            cnt_loc = (int*)(ws);
  int*            cnt_exp = (int*)(ws + 80000);
  int*            nbr_loc = (int*)(ws + 880064);
  unsigned short* nbr_exp = (unsigned short*)(ws + 11120064);
  _Float16*       Ylh     = (_Float16*)(ws + 23920064);
  _Float16*       Y2fh    = (_Float16*)(ws + 26480064);
  float*          z_loc   = (float*)(ws + 29040064);
  _Float16*       PH      = (_Float16*)(ws + 34160064);
  _Float16*       W1rT16  = (_Float16*)(ws + 36720064);
  _Float16*       W1lrT16 = (_Float16*)(ws + 36728256);
  _Float16*       WfqT16  = (_Float16*)(ws + 36736448);
  _Float16*       Wt2H16  = (_Float16*)(ws + 36761024);
  _Float16*       WpH16   = (_Float16*)(ws + 36769216);
  _Float16*       ZE      = (_Float16*)(ws + 39280064);
  _Float16*       TH      = (_Float16*)(ws + 64880064);
  u32*            expQ    = (u32*)(ws + 64880064);
  u32*            locQ    = (u32*)(ws + 72220096);
  int*            qcnt    = (int*)(ws + 79551936);
  int*            flbk    = (int*)(ws + 79553552);
  u64*            flbkQ   = (u64*)(ws + 79554048);
  float*          Wf_q    = (float*)(ws + 90480064);
  float*          Wf_y2   = (float*)(ws + 90496448);
  float*          Wf_t2   = (float*)(ws + 90512832);
  float*          Wf_p    = (float*)(ws + 90529216);
  float*          bf_q    = (float*)(ws + 90545600);
  float*          bf_p    = (float*)(ws + 90545856);
  float*          out     = (float*)d_out;

  (void)hipMemsetAsync(ws + 79551936, 0, 2048, stream);

  // ---- CSR fill (loc rows sorted by expert id) ----
  bin_kernel<<<NBIN, 256, 0, stream>>>(src, dst, expQ, locQ, qcnt, flbk, flbkQ);
  build_kernel<<<NBE + NBL, 256, 0, stream>>>(expQ, locQ, qcnt,
      nbr_exp, nbr_loc, cnt_exp, cnt_loc);
  prep_kernel<<<1258, 256, 0, stream>>>(W2r_of, W2l_of, W2l_rev, W2r_rev,
                                        dW1, b2_of, b2_rev,
                                        Wf_q, Wf_y2, Wf_t2, Wf_p, bf_q, bf_p,
                                        flbk, flbkQ, nbr_exp, nbr_loc,
                                        cnt_exp, cnt_loc,
                                        emb_loc, Ylh, W1l_of,
                                        W1r_of, W1l_rev,
                                        W1rT16, W1lrT16, WfqT16,
                                        Wt2H16, WpH16);

  // passA: ZE = relu(emb_exp@W1r_of + gatherE(Ylh) + b1_of); TH = emb_exp@W1l_rev
  mfma_pass_kernel<<<NEXP / 16, 256, 0, stream>>>(nbr_exp, cnt_exp, Ylh,
      emb_exp, (const _Float16*)nullptr, ZE, W1rT16, b1_of, 1, TH, W1lrT16);
  // loc pass 1: z_loc = relu(gatherL(TH) + emb_loc@W1r_rev + b1_rev)
  loc_gather_kernel<<<2048, 256, 0, stream>>>(nbr_loc, cnt_loc, TH,
      emb_loc, z_loc, W1r_rev, b1_rev, NLOC, 1);
  // loc pass 2: PH = gatherL(ZE)@Wf_t2 + z_loc@Wf_p + bf_p  (fold, r7-valid)
  loc_ph_kernel<<<2048, 256, 0, stream>>>(nbr_loc, cnt_loc, ZE,
      z_loc, PH, Wt2H16, WpH16, bf_p);
  // Y2fh = z_loc @ Wf_y2
  dense_linear_kernel<<<1280, 256, 0, stream>>>(z_loc, Y2fh, Wf_y2, NLOC);
  // passB: Qh = ZE@Wf_q + gatherE(Y2fh) + bf_q  (in-place, single MFMA)
  mfma_pass_kernel<<<NEXP / 16, 256, 0, stream>>>(nbr_exp, cnt_exp, Y2fh,
      (const float*)nullptr, ZE, ZE, WfqT16, bf_q, 0,
      (_Float16*)nullptr, (const _Float16*)nullptr);
  // edge decode
  edge_kernel<<<2048, 256, 0, stream>>>(row, col, PH, ZE,
                                        db1, dW2, db2, out);
}

// Round 12
// 622.167 us; speedup vs baseline: 1.6069x; 1.0296x over previous
//
#include <hip/hip_runtime.h>

#define H 64
#define NE 1500000
#define NLOC 20000
#define NEXP 200000
#define NL 400000
#define PAD_E 32
#define PAD_L 128

// ---- bucket-sort fill geometry ----
#define EB 896
#define NBE 224
#define LB 112
#define NBL 179
#define BIN_CHUNK 2048
#define NBIN ((NE + BIN_CHUNK - 1) / BIN_CHUNK)   // 733
#define EBSLOT 28
#define LBSLOT 32
#define ECAP 8192
#define LCAP 10240
#define FCAP 4096

// ---- workspace layout (bytes) ----  (r6 layout + Wt2/Wp f16 copies)
#define WS_NEED 90546112ULL

typedef int vint4 __attribute__((ext_vector_type(4)));
typedef _Float16 f16x8 __attribute__((ext_vector_type(8)));
typedef _Float16 f16x4 __attribute__((ext_vector_type(4)));
typedef float f32x4 __attribute__((ext_vector_type(4)));
typedef unsigned int u32;
typedef unsigned short u16;
typedef unsigned long long u64;

__device__ __forceinline__ float bcastf(float v, int k) {
  return __int_as_float(__builtin_amdgcn_readlane(__float_as_int(v), k));
}
__device__ __forceinline__ int bcasti(int v, int k) {
  return __builtin_amdgcn_readlane(v, k);
}
__device__ __forceinline__ int sel4(int g, int n0, int n1, int n2, int n3) {
  return (g & 2) ? ((g & 1) ? n3 : n2) : ((g & 1) ? n1 : n0);
}

// ---------------- bucket-sort fill, pass 1: bin edges ----------------
__global__ __launch_bounds__(256) void bin_kernel(
    const int* __restrict__ src, const int* __restrict__ dst,
    u32* __restrict__ expQ, u32* __restrict__ locQ,
    int* __restrict__ qcnt, int* __restrict__ flbk_cnt,
    u64* __restrict__ flbkQ)
{
  __shared__ u32 eb[NBE * EBSLOT];
  __shared__ u32 lb[NBL * LBSLOT];
  __shared__ int ec[NBE], lc[NBL], ebase[NBE], lbase[NBL];

  const int tid = threadIdx.x;
  for (int i = tid; i < NBE; i += 256) ec[i] = 0;
  for (int i = tid; i < NBL; i += 256) lc[i] = 0;
  __syncthreads();

  const long base = (long)blockIdx.x * BIN_CHUNK + tid * 8;
  if (base < NE) {
    vint4 s0 = __builtin_nontemporal_load((const vint4*)(src + base));
    vint4 s1 = __builtin_nontemporal_load((const vint4*)(src + base + 4));
    vint4 d0 = __builtin_nontemporal_load((const vint4*)(dst + base));
    vint4 d1 = __builtin_nontemporal_load((const vint4*)(dst + base + 4));
    int ss[8] = {s0.x, s0.y, s0.z, s0.w, s1.x, s1.y, s1.z, s1.w};
    int dd[8] = {d0.x, d0.y, d0.z, d0.w, d1.x, d1.y, d1.z, d1.w};
#pragma unroll
    for (int k = 0; k < 8; k++) {
      const u32 d = (u32)dd[k], s = (u32)ss[k];
      {
        const u32 b = d / (u32)EB;
        const int pos = atomicAdd(&ec[b], 1);
        if (pos < EBSLOT) {
          eb[b * EBSLOT + pos] = ((d - b * EB) << 16) | s;
        } else {
          int fi = atomicAdd(flbk_cnt, 1);
          if (fi < FCAP) flbkQ[fi] = ((u64)d << 32) | (u64)s;
        }
      }
      {
        const u32 b = s / (u32)LB;
        const int pos = atomicAdd(&lc[b], 1);
        if (pos < LBSLOT) {
          lb[b * LBSLOT + pos] = ((s - b * LB) << 18) | d;
        } else {
          int fi = atomicAdd(flbk_cnt, 1);
          if (fi < FCAP) flbkQ[fi] = (1ULL << 63) | ((u64)s << 32) | (u64)d;
        }
      }
    }
  }
  __syncthreads();

  for (int i = tid; i < NBE; i += 256) {
    const int c = min(ec[i], EBSLOT);
    ebase[i] = c ? atomicAdd(&qcnt[i], c) : 0;
  }
  for (int i = tid; i < NBL; i += 256) {
    const int c = min(lc[i], LBSLOT);
    lbase[i] = c ? atomicAdd(&qcnt[NBE + i], c) : 0;
  }
  __syncthreads();

  const int wid = tid >> 6, ln = tid & 63;
  for (int b = wid; b < NBE; b += 4) {
    const int c = min(ec[b], EBSLOT);
    if (ln < c) {
      const int idx = ebase[b] + ln;
      const u32 r = eb[b * EBSLOT + ln];
      if (idx < ECAP) {
        expQ[(long)b * ECAP + idx] = r;
      } else {
        int fi = atomicAdd(flbk_cnt, 1);
        if (fi < FCAP)
          flbkQ[fi] = ((u64)(b * EB + (r >> 16)) << 32) | (u64)(r & 0xFFFF);
      }
    }
  }
  for (int b = wid; b < NBL; b += 4) {
    const int c = min(lc[b], LBSLOT);
    if (ln < c) {
      const int idx = lbase[b] + ln;
      const u32 r = lb[b * LBSLOT + ln];
      if (idx < LCAP) {
        locQ[(long)b * LCAP + idx] = r;
      } else {
        int fi = atomicAdd(flbk_cnt, 1);
        if (fi < FCAP)
          flbkQ[fi] = (1ULL << 63) | ((u64)(b * LB + (r >> 18)) << 32) |
                      (u64)(r & 0x3FFFF);
      }
    }
  }
}

// ---------------- bucket-sort fill, pass 2: build padded CSR ----------------
// loc rows SORTED by expert id (bitonic min/max network -> permutation;
// mean is order-invariant). Sequential walk over sorted lists = implicit
// quantile alignment across waves (r11: FETCH 375->235 MB measured).
__global__ __launch_bounds__(256) void build_kernel(
    const u32* __restrict__ expQ, const u32* __restrict__ locQ,
    const int* __restrict__ qcnt,
    u16* __restrict__ nbr_exp, int* __restrict__ nbr_loc,
    int* __restrict__ cnt_exp, int* __restrict__ cnt_loc)
{
  __shared__ char ldsraw[60928];
  const int tid = threadIdx.x;
  if (blockIdx.x < NBE) {
    const int b = blockIdx.x;
    u16* rows = (u16*)ldsraw;
    int* cnts = (int*)(ldsraw + 57344);
    for (int i = tid; i < EB; i += 256) cnts[i] = 0;
    __syncthreads();
    const int n = min(qcnt[b], ECAP);
    for (int i = tid; i < n; i += 256) {
      const u32 r = expQ[(long)b * ECAP + i];
      const int nl = (int)(r >> 16);
      const int pos = atomicAdd(&cnts[nl], 1);
      if (pos < PAD_E) rows[nl * PAD_E + pos] = (u16)(r & 0xFFFF);
    }
    __syncthreads();
    const int node0 = b * EB;
    const int nn = min(EB, NEXP - node0);
    u32* grows = (u32*)(nbr_exp + (long)node0 * PAD_E);
    const u32* lrows = (const u32*)rows;
    for (int j = tid; j < nn * (PAD_E / 2); j += 256) grows[j] = lrows[j];
    for (int i = tid; i < nn; i += 256) cnt_exp[node0 + i] = cnts[i];
  } else {
    const int b = blockIdx.x - NBE;
    int* rows = (int*)ldsraw;
    int* cnts = (int*)(ldsraw + 57344);
    for (int i = tid; i < LB; i += 256) cnts[i] = 0;
    for (int i = tid; i < LB * PAD_L; i += 256) rows[i] = 0x3FFFF;  // pad
    __syncthreads();
    const int n = min(qcnt[NBE + b], LCAP);
    for (int i = tid; i < n; i += 256) {
      const u32 r = locQ[(long)b * LCAP + i];
      const int sl = (int)(r >> 18);
      const int pos = atomicAdd(&cnts[sl], 1);
      if (pos < PAD_L) rows[sl * PAD_L + pos] = (int)(r & 0x3FFFF);
    }
    __syncthreads();
    const int ln = tid & 63, wd = tid >> 6;
    for (int r = wd; r < LB; r += 4) {
      int* row = rows + r * PAD_L;
      int v0 = row[ln], v1 = row[64 + ln];
      for (int k = 2; k <= 128; k <<= 1) {
        for (int j = k >> 1; j >= 1; j >>= 1) {
          if (j == 64) {
            const int a = min(v0, v1), bmx = max(v0, v1);
            v0 = a; v1 = bmx;
          } else {
            const int p0 = __shfl_xor(v0, j);
            const int p1 = __shfl_xor(v1, j);
            const bool up = ((ln & j) == 0);
            const bool a0 = ((ln & k) == 0);
            const bool a1 = (((ln + 64) & k) == 0);
            v0 = (up == a0) ? min(v0, p0) : max(v0, p0);
            v1 = (up == a1) ? min(v1, p1) : max(v1, p1);
          }
        }
      }
      row[ln] = v0; row[64 + ln] = v1;
    }
    __syncthreads();
    const int node0 = b * LB;
    const int nn = min(LB, NLOC - node0);
    int* grows = nbr_loc + (long)node0 * PAD_L;
    for (int j = tid; j < nn * PAD_L; j += 256) grows[j] = rows[j];
    for (int i = tid; i < nn; i += 256) cnt_loc[node0 + i] = cnts[i];
  }
}

// prep_kernel: folds + f16 weight copies + fallback drain + dense Ylh.
__global__ __launch_bounds__(256) void prep_kernel(
    const float* __restrict__ W2r_of, const float* __restrict__ W2l_of,
    const float* __restrict__ W2l_rev, const float* __restrict__ W2r_rev,
    const float* __restrict__ dW1, const float* __restrict__ b2_of,
    const float* __restrict__ b2_rev,
    float* __restrict__ Wf_q, float* __restrict__ Wf_y2,
    float* __restrict__ Wf_t2, float* __restrict__ Wf_p,
    float* __restrict__ bf_q, float* __restrict__ bf_p,
    const int* __restrict__ flbk_cnt, const u64* __restrict__ flbkQ,
    u16* __restrict__ nbr_exp, int* __restrict__ nbr_loc,
    int* __restrict__ cnt_exp, int* __restrict__ cnt_loc,
    const float* __restrict__ emb_loc, _Float16* __restrict__ Ylh,
    const float* __restrict__ W1l_of,
    const float* __restrict__ W1r_of, const float* __restrict__ W1l_rev,
    _Float16* __restrict__ W1rT16, _Float16* __restrict__ W1lrT16,
    _Float16* __restrict__ WfqT16,
    _Float16* __restrict__ Wt2H16, _Float16* __restrict__ WpH16)
{
  const int lane = threadIdx.x & 63;
  const int w = threadIdx.x >> 6;
  const float* dW1a = dW1;
  const float* dW1b = dW1 + H * H;
  if (blockIdx.x < 4) {
    const float* A; const float* B; float* C;
    _Float16* CT; _Float16* CH;
    switch (blockIdx.x) {
      case 0:  A = W2r_of;  B = dW1b; C = Wf_q;  CT = WfqT16; CH = nullptr; break;
      case 1:  A = W2l_of;  B = dW1b; C = Wf_y2; CT = nullptr; CH = nullptr; break;
      case 2:  A = W2l_rev; B = dW1a; C = Wf_t2; CT = nullptr; CH = Wt2H16; break;
      default: A = W2r_rev; B = dW1a; C = Wf_p;  CT = nullptr; CH = WpH16;  break;
    }
    float b[H];
#pragma unroll
    for (int k = 0; k < H; k++) b[k] = B[k * H + lane];
    for (int r = w * 16; r < w * 16 + 16; r++) {
      const float xv = A[r * H + lane];
      float a0 = 0.f, a1 = 0.f;
#pragma unroll
      for (int k = 0; k < H; k += 2) {
        a0 += bcastf(xv, k)     * b[k];
        a1 += bcastf(xv, k + 1) * b[k + 1];
      }
      const float val = a0 + a1;
      C[r * H + lane] = val;
      if (CT) CT[(long)lane * H + r] = (_Float16)val;   // transposed f16
      if (CH) CH[(long)r * H + lane] = (_Float16)val;   // row-major f16
    }
  } else if (blockIdx.x == 4) {
    if (w < 2) {
      const float* bv_src = (w == 0) ? b2_of : b2_rev;
      const float* B      = (w == 0) ? dW1b  : dW1a;
      float* o            = (w == 0) ? bf_q  : bf_p;
      float wk[H];
#pragma unroll
      for (int k = 0; k < H; k++) wk[k] = B[k * H + lane];
      const float bv = bv_src[lane];
      float a = 0.f;
#pragma unroll
      for (int k = 0; k < H; k++) a += bcastf(bv, k) * wk[k];
      o[lane] = a;
    }
  } else if (blockIdx.x == 5) {
    const int n = min(*flbk_cnt, FCAP);
    for (int i = threadIdx.x; i < n; i += 256) {
      const u64 rec = flbkQ[i];
      const int node = (int)((rec >> 32) & 0x3FFFF);
      const int val  = (int)(rec & 0x3FFFF);
      if ((rec >> 63) == 0) {
        int pos = atomicAdd(&cnt_exp[node], 1);
        if (pos < PAD_E) nbr_exp[(long)node * PAD_E + pos] = (u16)val;
      } else {
        int pos = atomicAdd(&cnt_loc[node], 1);
        if (pos < PAD_L) nbr_loc[(long)node * PAD_L + pos] = val;
      }
    }
  } else if (blockIdx.x < 8) {
    // f16 transposes for MFMA B-fragments
    const float* S = (blockIdx.x == 6) ? W1r_of : W1l_rev;
    _Float16* D    = (blockIdx.x == 6) ? W1rT16 : W1lrT16;
    for (int k = w * 16; k < w * 16 + 16; k++)
      D[(long)lane * H + k] = (_Float16)S[(long)k * H + lane];
  } else {
    // dense: Ylh = emb_loc @ W1l_of (fp16 out), grid-stride 4 rows/wave
    float wreg[H];
#pragma unroll
    for (int k = 0; k < H; k++) wreg[k] = W1l_of[k * H + lane];
    const int gw2 = (blockIdx.x - 8) * 4 + w;       // 0..4999
    for (int r = gw2; r < NLOC; r += 5000) {
      const float xv = emb_loc[(long)r * H + lane];
      float a0 = 0.f, a1 = 0.f;
#pragma unroll
      for (int k = 0; k < H; k += 2) {
        a0 += bcastf(xv, k)     * wreg[k];
        a1 += bcastf(xv, k + 1) * wreg[k + 1];
      }
      Ylh[(long)r * H + lane] = (_Float16)(a0 + a1);
    }
  }
}

// out16 = x @ W (no bias); fp32 in, fp16 out.
__global__ __launch_bounds__(256, 4) void dense_linear_kernel(
    const float* __restrict__ x, _Float16* __restrict__ out16,
    const float* __restrict__ W, int n)
{
  const int lane = threadIdx.x & 63;
  const int gw = (blockIdx.x * 256 + threadIdx.x) >> 6;
  const int nw = (gridDim.x * 256) >> 6;
  float w[H];
#pragma unroll
  for (int k = 0; k < H; k++) w[k] = W[k * H + lane];
  for (int i = gw; i < n; i += nw) {
    const float xv = x[i * H + lane];
    float a0 = 0.f, a1 = 0.f;
#pragma unroll
    for (int k = 0; k < H; k += 2) {
      a0 += bcastf(xv, k)     * w[k];
      a1 += bcastf(xv, k + 1) * w[k + 1];
    }
    out16[i * H + lane] = (_Float16)(a0 + a1);
  }
}

// Exp-side MFMA pass (dual-B optional, gather/bias/relu optional). r6 form.
__global__ __launch_bounds__(256, 4) void mfma_pass_kernel(
    const u16* __restrict__ nbr, const int* __restrict__ cnt,
    const _Float16* __restrict__ y,
    const float* a32, const _Float16* a16,
    _Float16* out1, const _Float16* __restrict__ W1T,
    const float* __restrict__ bias, int relu,
    _Float16* out2, const _Float16* __restrict__ W2T)
{
  const int w = threadIdx.x >> 6;
  const int lane = threadIdx.x & 63;
  const int q = lane >> 4;
  const int cidx = lane & 15;
  const int rb = blockIdx.x * 16;

  __shared__ float Gs[16 * 68];

  const _Float16* bt1 = W1T + (long)(w * 16 + cidx) * H;
  f16x8 b1lo = *(const f16x8*)(bt1 + q * 8);
  f16x8 b1hi = *(const f16x8*)(bt1 + 32 + q * 8);
  f16x8 b2lo, b2hi;
  if (out2) {
    const _Float16* bt2 = W2T + (long)(w * 16 + cidx) * H;
    b2lo = *(const f16x8*)(bt2 + q * 8);
    b2hi = *(const f16x8*)(bt2 + 32 + q * 8);
  }

  f16x8 a0, a1;
  if (a16) {
    const _Float16* ar = a16 + (long)(rb + cidx) * H;
    a0 = *(const f16x8*)(ar + q * 8);
    a1 = *(const f16x8*)(ar + 32 + q * 8);
  } else {
    const float* ar = a32 + (long)(rb + cidx) * H;
    f32x4 v0 = *(const f32x4*)(ar + q * 8);
    f32x4 v1 = *(const f32x4*)(ar + q * 8 + 4);
    f32x4 v2 = *(const f32x4*)(ar + 32 + q * 8);
    f32x4 v3 = *(const f32x4*)(ar + 32 + q * 8 + 4);
#pragma unroll
    for (int j = 0; j < 4; j++) {
      a0[j] = (_Float16)v0[j];
      a0[j + 4] = (_Float16)v1[j];
      a1[j] = (_Float16)v2[j];
      a1[j + 4] = (_Float16)v3[j];
    }
  }

  if (y) {
    const int i0r = rb + w * 4;
    const int g = lane >> 4;
    const int sub = lane & 15;
    int c4v[4];
#pragma unroll
    for (int rr = 0; rr < 4; rr++) c4v[rr] = cnt[i0r + rr];
    int id4[4];
#pragma unroll
    for (int rr = 0; rr < 4; rr++) {
      const int c = min(c4v[rr], PAD_E);
      id4[rr] = (lane < c) ? (int)nbr[(long)(i0r + rr) * PAD_E + lane] : 0;
    }
#pragma unroll
    for (int rr = 0; rr < 4; rr++) {
      const int cc = min(c4v[rr], PAD_E);
      const int id = id4[rr];
      const int kl = cc - 1;
      float s0 = 0.f, s1 = 0.f, s2 = 0.f, s3 = 0.f;
      for (int k = 0; k < cc; k += 4) {
        const int n0 = bcasti(id, k);
        const int n1 = bcasti(id, min(k + 1, kl));
        const int n2 = bcasti(id, min(k + 2, kl));
        const int n3 = bcasti(id, min(k + 3, kl));
        const int ns = sel4(g, n0, n1, n2, n3);
        const f16x4 v = *(const f16x4*)(y + (long)ns * H + sub * 4);
        const float msk = (k + g < cc) ? 1.0f : 0.0f;
        s0 = fmaf(msk, (float)v[0], s0);
        s1 = fmaf(msk, (float)v[1], s1);
        s2 = fmaf(msk, (float)v[2], s2);
        s3 = fmaf(msk, (float)v[3], s3);
      }
      s0 += __shfl_xor(s0, 16); s0 += __shfl_xor(s0, 32);
      s1 += __shfl_xor(s1, 16); s1 += __shfl_xor(s1, 32);
      s2 += __shfl_xor(s2, 16); s2 += __shfl_xor(s2, 32);
      s3 += __shfl_xor(s3, 16); s3 += __shfl_xor(s3, 32);
      const float inv = 1.0f / fmaxf((float)c4v[rr], 1.0f);
      if (lane < 16) {
        float* gp = &Gs[(w * 4 + rr) * 68 + 4 * lane];
        gp[0] = s0 * inv; gp[1] = s1 * inv;
        gp[2] = s2 * inv; gp[3] = s3 * inv;
      }
    }
  }

  f32x4 acc1 = {0.f, 0.f, 0.f, 0.f};
  acc1 = __builtin_amdgcn_mfma_f32_16x16x32_f16(a0, b1lo, acc1, 0, 0, 0);
  acc1 = __builtin_amdgcn_mfma_f32_16x16x32_f16(a1, b1hi, acc1, 0, 0, 0);
  f32x4 acc2 = {0.f, 0.f, 0.f, 0.f};
  if (out2) {
    acc2 = __builtin_amdgcn_mfma_f32_16x16x32_f16(a0, b2lo, acc2, 0, 0, 0);
    acc2 = __builtin_amdgcn_mfma_f32_16x16x32_f16(a1, b2hi, acc2, 0, 0, 0);
  }

  const float bj = bias ? bias[w * 16 + cidx] : 0.f;
  __syncthreads();
#pragma unroll
  for (int reg = 0; reg < 4; reg++) {
    const int r = q * 4 + reg;
    float v = acc1[reg] + bj;
    if (y) v += Gs[r * 68 + w * 16 + cidx];
    if (relu) v = fmaxf(v, 0.f);
    out1[(long)(rb + r) * H + w * 16 + cidx] = (_Float16)v;
    if (out2)
      out2[(long)(rb + r) * H + w * 16 + cidx] = (_Float16)acc2[reg];
  }
}

// loc pass 1 (r6's proven quad-row kernel, byte-identical config):
// z = relu(mean-gather(T) + x@Wr + b). Sorted lists supply band locality.
__global__ __launch_bounds__(256, 4) void loc_gather_kernel(
    const int* __restrict__ nbr, const int* __restrict__ cnt,
    const _Float16* __restrict__ T, const float* __restrict__ x,
    float* __restrict__ out32,
    const float* __restrict__ Wr, const float* __restrict__ bias,
    int n, int relu)
{
  const int lane = threadIdx.x & 63;
  const int gw = (blockIdx.x * 256 + threadIdx.x) >> 6;
  const int nw = (gridDim.x * 256) >> 6;
  const int g = lane >> 4;
  const int sub = lane & 15;
  float wr[H];
#pragma unroll
  for (int k = 0; k < H; k++) wr[k] = Wr[k * H + lane];
  const float bj = bias[lane];
  for (int i = gw; i < n; i += nw) {
    const int c = cnt[i];
    const int cc = min(c, PAD_L);
    const int* nb = nbr + (long)i * PAD_L;
    float s0 = 0.f, s1 = 0.f, s2 = 0.f, s3 = 0.f;
    float s4 = 0.f, s5 = 0.f, s6 = 0.f, s7 = 0.f;
    int e = 0;
    while (e < cc) {
      const int m = min(cc - e, 64);
      const int id = (lane < m) ? nb[e + lane] : 0;
      const int ml = m - 1;
      for (int k = 0; k < m; k += 8) {
        const int a0i = bcasti(id, k);
        const int a1i = bcasti(id, min(k + 1, ml));
        const int a2i = bcasti(id, min(k + 2, ml));
        const int a3i = bcasti(id, min(k + 3, ml));
        const int nsA = sel4(g, a0i, a1i, a2i, a3i);
        const f16x4 vA = *(const f16x4*)(T + (long)nsA * H + sub * 4);
        const int b0i = bcasti(id, min(k + 4, ml));
        const int b1i = bcasti(id, min(k + 5, ml));
        const int b2i = bcasti(id, min(k + 6, ml));
        const int b3i = bcasti(id, min(k + 7, ml));
        const int nsB = sel4(g, b0i, b1i, b2i, b3i);
        const f16x4 vB = *(const f16x4*)(T + (long)nsB * H + sub * 4);
        const float mA = (k + g < m) ? 1.0f : 0.0f;
        const float mB = (k + 4 + g < m) ? 1.0f : 0.0f;
        s0 = fmaf(mA, (float)vA[0], s0);
        s1 = fmaf(mA, (float)vA[1], s1);
        s2 = fmaf(mA, (float)vA[2], s2);
        s3 = fmaf(mA, (float)vA[3], s3);
        s4 = fmaf(mB, (float)vB[0], s4);
        s5 = fmaf(mB, (float)vB[1], s5);
        s6 = fmaf(mB, (float)vB[2], s6);
        s7 = fmaf(mB, (float)vB[3], s7);
      }
      e += m;
    }
    s0 += s4; s1 += s5; s2 += s6; s3 += s7;
    s0 += __shfl_xor(s0, 16); s0 += __shfl_xor(s0, 32);
    s1 += __shfl_xor(s1, 16); s1 += __shfl_xor(s1, 32);
    s2 += __shfl_xor(s2, 16); s2 += __shfl_xor(s2, 32);
    s3 += __shfl_xor(s3, 16); s3 += __shfl_xor(s3, 32);
    const int srcl = lane >> 2;
    const float v0 = __shfl(s0, srcl);
    const float v1 = __shfl(s1, srcl);
    const float v2 = __shfl(s2, srcl);
    const float v3 = __shfl(s3, srcl);
    const int r2 = lane & 3;
    const float sg = (r2 & 2) ? ((r2 & 1) ? v3 : v2) : ((r2 & 1) ? v1 : v0);
    const float agg = sg / fmaxf((float)c, 1.0f);
    const float xv = x[(long)i * H + lane];
    float a0 = 0.f, a1 = 0.f;
#pragma unroll
    for (int k = 0; k < H; k += 2) {
      a0 += bcastf(xv, k)     * wr[k];
      a1 += bcastf(xv, k + 1) * wr[k + 1];
    }
    float acc = agg + bj + a0 + a1;
    if (relu) acc = fmaxf(acc, 0.0f);
    out32[(long)i * H + lane] = acc;
  }
}

// loc pass 2 (fold applied, r7-validated): PH = mean-gather(ZE)@Wt2 +
// z_loc@Wp + bf_p. r6's quad-row gather body; LDS-f16 weights; bounds 6
// (r11's 184us was a (256,4)/64-VGPR occupancy bug — r8 got 40 VGPR @6).
__global__ __launch_bounds__(256, 6) void loc_ph_kernel(
    const int* __restrict__ nbr, const int* __restrict__ cnt,
    const _Float16* __restrict__ ZEt, const float* __restrict__ z_loc,
    _Float16* __restrict__ ph_out,
    const _Float16* __restrict__ Wt216, const _Float16* __restrict__ Wp16,
    const float* __restrict__ bfp)
{
  __shared__ _Float16 Wl[2 * 4096];   // 16KB
  const int tid = threadIdx.x;
  for (int j = tid * 8; j < 4096; j += 2048) {
    *(f16x8*)&Wl[j]        = *(const f16x8*)&Wt216[j];
    *(f16x8*)&Wl[4096 + j] = *(const f16x8*)&Wp16[j];
  }
  __syncthreads();

  const int lane = tid & 63;
  const int gw = (blockIdx.x * 256 + tid) >> 6;
  const int nw = (gridDim.x * 256) >> 6;
  const int g = lane >> 4;
  const int sub = lane & 15;
  const float bp = bfp[lane];
  for (int i = gw; i < NLOC; i += nw) {
    const int c = cnt[i];
    const int cc = min(c, PAD_L);
    const int* nb = nbr + (long)i * PAD_L;
    float s0 = 0.f, s1 = 0.f, s2 = 0.f, s3 = 0.f;
    float s4 = 0.f, s5 = 0.f, s6 = 0.f, s7 = 0.f;
    int e = 0;
    while (e < cc) {
      const int m = min(cc - e, 64);
      const int id = (lane < m) ? nb[e + lane] : 0;
      const int ml = m - 1;
      for (int k = 0; k < m; k += 8) {
        const int a0i = bcasti(id, k);
        const int a1i = bcasti(id, min(k + 1, ml));
        const int a2i = bcasti(id, min(k + 2, ml));
        const int a3i = bcasti(id, min(k + 3, ml));
        const int nsA = sel4(g, a0i, a1i, a2i, a3i);
        const f16x4 vA = *(const f16x4*)(ZEt + (long)nsA * H + sub * 4);
        const int b0i = bcasti(id, min(k + 4, ml));
        const int b1i = bcasti(id, min(k + 5, ml));
        const int b2i = bcasti(id, min(k + 6, ml));
        const int b3i = bcasti(id, min(k + 7, ml));
        const int nsB = sel4(g, b0i, b1i, b2i, b3i);
        const f16x4 vB = *(const f16x4*)(ZEt + (long)nsB * H + sub * 4);
        const float mA = (k + g < m) ? 1.0f : 0.0f;
        const float mB = (k + 4 + g < m) ? 1.0f : 0.0f;
        s0 = fmaf(mA, (float)vA[0], s0);
        s1 = fmaf(mA, (float)vA[1], s1);
        s2 = fmaf(mA, (float)vA[2], s2);
        s3 = fmaf(mA, (float)vA[3], s3);
        s4 = fmaf(mB, (float)vB[0], s4);
        s5 = fmaf(mB, (float)vB[1], s5);
        s6 = fmaf(mB, (float)vB[2], s6);
        s7 = fmaf(mB, (float)vB[3], s7);
      }
      e += m;
    }
    s0 += s4; s1 += s5; s2 += s6; s3 += s7;
    s0 += __shfl_xor(s0, 16); s0 += __shfl_xor(s0, 32);
    s1 += __shfl_xor(s1, 16); s1 += __shfl_xor(s1, 32);
    s2 += __shfl_xor(s2, 16); s2 += __shfl_xor(s2, 32);
    s3 += __shfl_xor(s3, 16); s3 += __shfl_xor(s3, 32);
    const int srcl = lane >> 2;
    const float v0 = __shfl(s0, srcl);
    const float v1 = __shfl(s1, srcl);
    const float v2 = __shfl(s2, srcl);
    const float v3 = __shfl(s3, srcl);
    const int r2 = lane & 3;
    const float sg = (r2 & 2) ? ((r2 & 1) ? v3 : v2) : ((r2 & 1) ? v1 : v0);
    const float gz = sg / fmaxf((float)c, 1.0f);
    const float zv = z_loc[(long)i * H + lane];
    float p0 = 0.f, p1 = 0.f;
#pragma unroll
    for (int k = 0; k < H; k += 2) {
      p0 = fmaf(bcastf(gz, k),     (float)Wl[k * H + lane], p0);
      p0 = fmaf(bcastf(zv, k),     (float)Wl[4096 + k * H + lane], p0);
      p1 = fmaf(bcastf(gz, k + 1), (float)Wl[(k + 1) * H + lane], p1);
      p1 = fmaf(bcastf(zv, k + 1), (float)Wl[4096 + (k + 1) * H + lane], p1);
    }
    ph_out[(long)i * H + lane] = (_Float16)(p0 + p1 + bp);
  }
}

// out[e] = sum_j relu(P[r,j] + Q[c,j] + db1[j]) * dW2[j] + db2  (P,Q fp16)
__global__ __launch_bounds__(256, 4) void edge_kernel(
    const int* __restrict__ row, const int* __restrict__ col,
    const _Float16* __restrict__ P, const _Float16* __restrict__ Q,
    const float* __restrict__ db1, const float* __restrict__ dW2,
    const float* __restrict__ db2, float* __restrict__ out)
{
  const int lane = threadIdx.x & 63;
  const int gw = (blockIdx.x * 256 + threadIdx.x) >> 6;
  const int nw = (gridDim.x * 256) >> 6;
  const int g = lane >> 4;
  const int sub = lane & 15;
  const f32x4 bj4 = *(const f32x4*)(db1 + 4 * sub);
  const f32x4 w24 = *(const f32x4*)(dW2 + 4 * sub);
  const float b2 = db2[0];
  for (int e = gw * 4; e < NL; e += nw * 4) {
    const int r0 = row[e], r1 = row[e + 1], r2i = row[e + 2], r3 = row[e + 3];
    const int c0 = col[e], c1 = col[e + 1], c2i = col[e + 2], c3 = col[e + 3];
    const int rs = sel4(g, r0, r1, r2i, r3);
    const int cs = sel4(g, c0, c1, c2i, c3);
    const f16x4 pv = *(const f16x4*)(P + (long)rs * H + sub * 4);
    const f16x4 qv = *(const f16x4*)(Q + (long)cs * H + sub * 4);
    float h = fmaxf((float)pv[0] + (float)qv[0] + bj4[0], 0.f) * w24[0]
            + fmaxf((float)pv[1] + (float)qv[1] + bj4[1], 0.f) * w24[1]
            + fmaxf((float)pv[2] + (float)qv[2] + bj4[2], 0.f) * w24[2]
            + fmaxf((float)pv[3] + (float)qv[3] + bj4[3], 0.f) * w24[3];
    h += __shfl_xor(h, 1);
    h += __shfl_xor(h, 2);
    h += __shfl_xor(h, 4);
    h += __shfl_xor(h, 8);
    if (sub == 0) out[e + g] = h + b2;
  }
}

extern "C" void kernel_launch(void* const* d_in, const int* in_sizes, int n_in,
                              void* d_out, int out_size, void* d_ws, size_t ws_size,
                              hipStream_t stream) {
  const float* emb_loc = (const float*)d_in[0];
  const float* emb_exp = (const float*)d_in[1];
  const float* W1l_of  = (const float*)d_in[2];
  const float* b1_of   = (const float*)d_in[3];
  const float* W1r_of  = (const float*)d_in[4];
  const float* W1l_rev = (const float*)d_in[5];
  const float* b1_rev  = (const float*)d_in[6];
  const float* W1r_rev = (const float*)d_in[7];
  const float* W2l_of  = (const float*)d_in[8];
  const float* b2_of   = (const float*)d_in[9];
  const float* W2r_of  = (const float*)d_in[10];
  const float* W2l_rev = (const float*)d_in[11];
  const float* b2_rev  = (const float*)d_in[12];
  const float* W2r_rev = (const float*)d_in[13];
  const float* dW1     = (const float*)d_in[14];
  const float* db1     = (const float*)d_in[15];
  const float* dW2     = (const float*)d_in[16];
  const float* db2     = (const float*)d_in[17];
  const int*   edge_of = (const int*)d_in[18];
  const int*   eli     = (const int*)d_in[20];

  const int* src = edge_of;
  const int* dst = edge_of + NE;
  const int* row = eli;
  const int* col = eli + NL;

  if (ws_size < WS_NEED) return;

  char* ws = (char*)d_ws;
  int*            cnt_loc = (int*)(ws);
  int*            cnt_exp = (int*)(ws + 80000);
  int*            nbr_loc = (int*)(ws + 880064);
  unsigned short* nbr_exp = (unsigned short*)(ws + 11120064);
  _Float16*       Ylh     = (_Float16*)(ws + 23920064);
  _Float16*       Y2fh    = (_Float16*)(ws + 26480064);
  float*          z_loc   = (float*)(ws + 29040064);
  _Float16*       PH      = (_Float16*)(ws + 34160064);
  _Float16*       W1rT16  = (_Float16*)(ws + 36720064);
  _Float16*       W1lrT16 = (_Float16*)(ws + 36728256);
  _Float16*       WfqT16  = (_Float16*)(ws + 36736448);
  _Float16*       Wt2H16  = (_Float16*)(ws + 36761024);
  _Float16*       WpH16   = (_Float16*)(ws + 36769216);
  _Float16*       ZE      = (_Float16*)(ws + 39280064);
  _Float16*       TH      = (_Float16*)(ws + 64880064);
  u32*            expQ    = (u32*)(ws + 64880064);
  u32*            locQ    = (u32*)(ws + 72220096);
  int*            qcnt    = (int*)(ws + 79551936);
  int*            flbk    = (int*)(ws + 79553552);
  u64*            flbkQ   = (u64*)(ws + 79554048);
  float*          Wf_q    = (float*)(ws + 90480064);
  float*          Wf_y2   = (float*)(ws + 90496448);
  float*          Wf_t2   = (float*)(ws + 90512832);
  float*          Wf_p    = (float*)(ws + 90529216);
  float*          bf_q    = (float*)(ws + 90545600);
  float*          bf_p    = (float*)(ws + 90545856);
  float*          out     = (float*)d_out;

  (void)hipMemsetAsync(ws + 79551936, 0, 2048, stream);

  // ---- CSR fill (loc rows sorted by expert id) ----
  bin_kernel<<<NBIN, 256, 0, stream>>>(src, dst, expQ, locQ, qcnt, flbk, flbkQ);
  build_kernel<<<NBE + NBL, 256, 0, stream>>>(expQ, locQ, qcnt,
      nbr_exp, nbr_loc, cnt_exp, cnt_loc);
  prep_kernel<<<1258, 256, 0, stream>>>(W2r_of, W2l_of, W2l_rev, W2r_rev,
                                        dW1, b2_of, b2_rev,
                                        Wf_q, Wf_y2, Wf_t2, Wf_p, bf_q, bf_p,
                                        flbk, flbkQ, nbr_exp, nbr_loc,
                                        cnt_exp, cnt_loc,
                                        emb_loc, Ylh, W1l_of,
                                        W1r_of, W1l_rev,
                                        W1rT16, W1lrT16, WfqT16,
                                        Wt2H16, WpH16);

  // passA: ZE = relu(emb_exp@W1r_of + gatherE(Ylh) + b1_of); TH = emb_exp@W1l_rev
  mfma_pass_kernel<<<NEXP / 16, 256, 0, stream>>>(nbr_exp, cnt_exp, Ylh,
      emb_exp, (const _Float16*)nullptr, ZE, W1rT16, b1_of, 1, TH, W1lrT16);
  // loc pass 1: z_loc = relu(gatherL(TH) + emb_loc@W1r_rev + b1_rev)
  loc_gather_kernel<<<2048, 256, 0, stream>>>(nbr_loc, cnt_loc, TH,
      emb_loc, z_loc, W1r_rev, b1_rev, NLOC, 1);
  // loc pass 2: PH = gatherL(ZE)@Wf_t2 + z_loc@Wf_p + bf_p  (fold, r7-valid)
  loc_ph_kernel<<<2048, 256, 0, stream>>>(nbr_loc, cnt_loc, ZE,
      z_loc, PH, Wt2H16, WpH16, bf_p);
  // Y2fh = z_loc @ Wf_y2
  dense_linear_kernel<<<1280, 256, 0, stream>>>(z_loc, Y2fh, Wf_y2, NLOC);
  // passB: Qh = ZE@Wf_q + gatherE(Y2fh) + bf_q  (in-place, single MFMA)
  mfma_pass_kernel<<<NEXP / 16, 256, 0, stream>>>(nbr_exp, cnt_exp, Y2fh,
      (const float*)nullptr, ZE, ZE, WfqT16, bf_q, 0,
      (_Float16*)nullptr, (const _Float16*)nullptr);
  // edge decode
  edge_kernel<<<2048, 256, 0, stream>>>(row, col, PH, ZE,
                                        db1, dW2, db2, out);
}

// Round 13
// 500.659 us; speedup vs baseline: 1.9969x; 1.2427x over previous
//
#include <hip/hip_runtime.h>

#define H 64
#define NE 1500000
#define NLOC 20000
#define NEXP 200000
#define NL 400000
#define PAD_E 32
#define PAD_L 128

// ---- bucket-sort fill geometry ----
#define EB 896
#define NBE 224
#define LB 112
#define NBL 179
#define BIN_CHUNK 2048
#define NBIN ((NE + BIN_CHUNK - 1) / BIN_CHUNK)   // 733
#define EBSLOT 28
#define LBSLOT 32
#define ECAP 8192
#define LCAP 10240
#define FCAP 4096

// ---- workspace layout (bytes) ----
// cnt_loc [0,80000)  cnt_exp [80000,880000)
// nbr_loc [880064,11120064)  nbr_exp(u16) [11120064,23920064)
// Ylh(f16)  [23920064,26480064)   Y2fh(f16) [26480064,29040064)
// z_loc(f32)[29040064,34160064)   PH(f16)   [34160064,36720064)
//   fp16-transposed MFMA B weights (in the PH..ZE hole):
//   W1rT16 [36720064,+8192) W1lrT16 [36728256,+8192)
//   WfqT16 [36736448,+8192) Wft2T16 [36744640,+8192)
// ZE(f16)   [39280064,64880064)   z_exph -> Qh (in-place)
// TH(f16)   [64880064,90480064)   T1h -> T2'h
//   (aliased pre-mfma: expQ [64880064,72220096) locQ [72220096,79551936)
//    qcnt [79551936,+1612) flbk_cnt [79553552) flbkQ [79554048,+32768))
// Wf_q [90480064) Wf_y2 [90496448) Wf_t2 [90512832) Wf_p [90529216)
// bf_q [90545600) bf_p [90545856)
#define WS_NEED 90546112ULL

typedef int vint4 __attribute__((ext_vector_type(4)));
typedef _Float16 f16x8 __attribute__((ext_vector_type(8)));
typedef _Float16 f16x4 __attribute__((ext_vector_type(4)));
typedef float f32x4 __attribute__((ext_vector_type(4)));
typedef unsigned int u32;
typedef unsigned short u16;
typedef unsigned long long u64;

__device__ __forceinline__ float bcastf(float v, int k) {
  return __int_as_float(__builtin_amdgcn_readlane(__float_as_int(v), k));
}
__device__ __forceinline__ int bcasti(int v, int k) {
  return __builtin_amdgcn_readlane(v, k);
}
__device__ __forceinline__ int sel4(int g, int n0, int n1, int n2, int n3) {
  return (g & 2) ? ((g & 1) ? n3 : n2) : ((g & 1) ? n1 : n0);
}

// ---------------- bucket-sort fill, pass 1: bin edges ----------------
__global__ __launch_bounds__(256) void bin_kernel(
    const int* __restrict__ src, const int* __restrict__ dst,
    u32* __restrict__ expQ, u32* __restrict__ locQ,
    int* __restrict__ qcnt, int* __restrict__ flbk_cnt,
    u64* __restrict__ flbkQ)
{
  __shared__ u32 eb[NBE * EBSLOT];
  __shared__ u32 lb[NBL * LBSLOT];
  __shared__ int ec[NBE], lc[NBL], ebase[NBE], lbase[NBL];

  const int tid = threadIdx.x;
  for (int i = tid; i < NBE; i += 256) ec[i] = 0;
  for (int i = tid; i < NBL; i += 256) lc[i] = 0;
  __syncthreads();

  const long base = (long)blockIdx.x * BIN_CHUNK + tid * 8;
  if (base < NE) {
    vint4 s0 = __builtin_nontemporal_load((const vint4*)(src + base));
    vint4 s1 = __builtin_nontemporal_load((const vint4*)(src + base + 4));
    vint4 d0 = __builtin_nontemporal_load((const vint4*)(dst + base));
    vint4 d1 = __builtin_nontemporal_load((const vint4*)(dst + base + 4));
    int ss[8] = {s0.x, s0.y, s0.z, s0.w, s1.x, s1.y, s1.z, s1.w};
    int dd[8] = {d0.x, d0.y, d0.z, d0.w, d1.x, d1.y, d1.z, d1.w};
#pragma unroll
    for (int k = 0; k < 8; k++) {
      const u32 d = (u32)dd[k], s = (u32)ss[k];
      {
        const u32 b = d / (u32)EB;
        const int pos = atomicAdd(&ec[b], 1);
        if (pos < EBSLOT) {
          eb[b * EBSLOT + pos] = ((d - b * EB) << 16) | s;
        } else {
          int fi = atomicAdd(flbk_cnt, 1);
          if (fi < FCAP) flbkQ[fi] = ((u64)d << 32) | (u64)s;
        }
      }
      {
        const u32 b = s / (u32)LB;
        const int pos = atomicAdd(&lc[b], 1);
        if (pos < LBSLOT) {
          lb[b * LBSLOT + pos] = ((s - b * LB) << 18) | d;
        } else {
          int fi = atomicAdd(flbk_cnt, 1);
          if (fi < FCAP) flbkQ[fi] = (1ULL << 63) | ((u64)s << 32) | (u64)d;
        }
      }
    }
  }
  __syncthreads();

  for (int i = tid; i < NBE; i += 256) {
    const int c = min(ec[i], EBSLOT);
    ebase[i] = c ? atomicAdd(&qcnt[i], c) : 0;
  }
  for (int i = tid; i < NBL; i += 256) {
    const int c = min(lc[i], LBSLOT);
    lbase[i] = c ? atomicAdd(&qcnt[NBE + i], c) : 0;
  }
  __syncthreads();

  const int wid = tid >> 6, ln = tid & 63;
  for (int b = wid; b < NBE; b += 4) {
    const int c = min(ec[b], EBSLOT);
    if (ln < c) {
      const int idx = ebase[b] + ln;
      const u32 r = eb[b * EBSLOT + ln];
      if (idx < ECAP) {
        expQ[(long)b * ECAP + idx] = r;
      } else {
        int fi = atomicAdd(flbk_cnt, 1);
        if (fi < FCAP)
          flbkQ[fi] = ((u64)(b * EB + (r >> 16)) << 32) | (u64)(r & 0xFFFF);
      }
    }
  }
  for (int b = wid; b < NBL; b += 4) {
    const int c = min(lc[b], LBSLOT);
    if (ln < c) {
      const int idx = lbase[b] + ln;
      const u32 r = lb[b * LBSLOT + ln];
      if (idx < LCAP) {
        locQ[(long)b * LCAP + idx] = r;
      } else {
        int fi = atomicAdd(flbk_cnt, 1);
        if (fi < FCAP)
          flbkQ[fi] = (1ULL << 63) | ((u64)(b * LB + (r >> 18)) << 32) |
                      (u64)(r & 0x3FFFF);
      }
    }
  }
}

// ---------------- bucket-sort fill, pass 2: build padded CSR ----------------
__global__ __launch_bounds__(256) void build_kernel(
    const u32* __restrict__ expQ, const u32* __restrict__ locQ,
    const int* __restrict__ qcnt,
    u16* __restrict__ nbr_exp, int* __restrict__ nbr_loc,
    int* __restrict__ cnt_exp, int* __restrict__ cnt_loc)
{
  __shared__ char ldsraw[60928];
  const int tid = threadIdx.x;
  if (blockIdx.x < NBE) {
    const int b = blockIdx.x;
    u16* rows = (u16*)ldsraw;
    int* cnts = (int*)(ldsraw + 57344);
    for (int i = tid; i < EB; i += 256) cnts[i] = 0;
    __syncthreads();
    const int n = min(qcnt[b], ECAP);
    for (int i = tid; i < n; i += 256) {
      const u32 r = expQ[(long)b * ECAP + i];
      const int nl = (int)(r >> 16);
      const int pos = atomicAdd(&cnts[nl], 1);
      if (pos < PAD_E) rows[nl * PAD_E + pos] = (u16)(r & 0xFFFF);
    }
    __syncthreads();
    const int node0 = b * EB;
    const int nn = min(EB, NEXP - node0);
    u32* grows = (u32*)(nbr_exp + (long)node0 * PAD_E);
    const u32* lrows = (const u32*)rows;
    for (int j = tid; j < nn * (PAD_E / 2); j += 256) grows[j] = lrows[j];
    for (int i = tid; i < nn; i += 256) cnt_exp[node0 + i] = cnts[i];
  } else {
    const int b = blockIdx.x - NBE;
    int* rows = (int*)ldsraw;
    int* cnts = (int*)(ldsraw + 57344);
    for (int i = tid; i < LB; i += 256) cnts[i] = 0;
    __syncthreads();
    const int n = min(qcnt[NBE + b], LCAP);
    for (int i = tid; i < n; i += 256) {
      const u32 r = locQ[(long)b * LCAP + i];
      const int sl = (int)(r >> 18);
      const int pos = atomicAdd(&cnts[sl], 1);
      if (pos < PAD_L) rows[sl * PAD_L + pos] = (int)(r & 0x3FFFF);
    }
    __syncthreads();
    const int node0 = b * LB;
    const int nn = min(LB, NLOC - node0);
    int* grows = nbr_loc + (long)node0 * PAD_L;
    for (int j = tid; j < nn * PAD_L; j += 256) grows[j] = rows[j];
    for (int i = tid; i < nn; i += 256) cnt_loc[node0 + i] = cnts[i];
  }
}

// prep_kernel: fold (blk 0-4, with fp16-transposed copies of Wf_q/Wf_t2) +
// fallback drain (blk 5) + fp16 transpose of W1r_of/W1l_rev (blk 6-7) +
// dense Ylh grid-stride (blk >=8).
__global__ __launch_bounds__(256) void prep_kernel(
    const float* __restrict__ W2r_of, const float* __restrict__ W2l_of,
    const float* __restrict__ W2l_rev, const float* __restrict__ W2r_rev,
    const float* __restrict__ dW1, const float* __restrict__ b2_of,
    const float* __restrict__ b2_rev,
    float* __restrict__ Wf_q, float* __restrict__ Wf_y2,
    float* __restrict__ Wf_t2, float* __restrict__ Wf_p,
    float* __restrict__ bf_q, float* __restrict__ bf_p,
    const int* __restrict__ flbk_cnt, const u64* __restrict__ flbkQ,
    u16* __restrict__ nbr_exp, int* __restrict__ nbr_loc,
    int* __restrict__ cnt_exp, int* __restrict__ cnt_loc,
    const float* __restrict__ emb_loc, _Float16* __restrict__ Ylh,
    const float* __restrict__ W1l_of,
    const float* __restrict__ W1r_of, const float* __restrict__ W1l_rev,
    _Float16* __restrict__ W1rT16, _Float16* __restrict__ W1lrT16,
    _Float16* __restrict__ WfqT16, _Float16* __restrict__ Wft2T16)
{
  const int lane = threadIdx.x & 63;
  const int w = threadIdx.x >> 6;
  const float* dW1a = dW1;
  const float* dW1b = dW1 + H * H;
  if (blockIdx.x < 4) {
    const float* A; const float* B; float* C; _Float16* CT;
    switch (blockIdx.x) {
      case 0:  A = W2r_of;  B = dW1b; C = Wf_q;  CT = WfqT16;  break;
      case 1:  A = W2l_of;  B = dW1b; C = Wf_y2; CT = nullptr; break;
      case 2:  A = W2l_rev; B = dW1a; C = Wf_t2; CT = Wft2T16; break;
      default: A = W2r_rev; B = dW1a; C = Wf_p;  CT = nullptr; break;
    }
    float b[H];
#pragma unroll
    for (int k = 0; k < H; k++) b[k] = B[k * H + lane];
    for (int r = w * 16; r < w * 16 + 16; r++) {
      const float xv = A[r * H + lane];
      float a0 = 0.f, a1 = 0.f;
#pragma unroll
      for (int k = 0; k < H; k += 2) {
        a0 += bcastf(xv, k)     * b[k];
        a1 += bcastf(xv, k + 1) * b[k + 1];
      }
      const float val = a0 + a1;
      C[r * H + lane] = val;
      if (CT) CT[(long)lane * H + r] = (_Float16)val;   // transposed fp16
    }
  } else if (blockIdx.x == 4) {
    if (w < 2) {
      const float* bv_src = (w == 0) ? b2_of : b2_rev;
      const float* B      = (w == 0) ? dW1b  : dW1a;
      float* o            = (w == 0) ? bf_q  : bf_p;
      float wk[H];
#pragma unroll
      for (int k = 0; k < H; k++) wk[k] = B[k * H + lane];
      const float bv = bv_src[lane];
      float a = 0.f;
#pragma unroll
      for (int k = 0; k < H; k++) a += bcastf(bv, k) * wk[k];
      o[lane] = a;
    }
  } else if (blockIdx.x == 5) {
    // drain fallback queue (rare Poisson-tail edges; keeps fill exact)
    const int n = min(*flbk_cnt, FCAP);
    for (int i = threadIdx.x; i < n; i += 256) {
      const u64 rec = flbkQ[i];
      const int node = (int)((rec >> 32) & 0x3FFFF);
      const int val  = (int)(rec & 0x3FFFF);
      if ((rec >> 63) == 0) {
        int pos = atomicAdd(&cnt_exp[node], 1);
        if (pos < PAD_E) nbr_exp[(long)node * PAD_E + pos] = (u16)val;
      } else {
        int pos = atomicAdd(&cnt_loc[node], 1);
        if (pos < PAD_L) nbr_loc[(long)node * PAD_L + pos] = val;
      }
    }
  } else if (blockIdx.x < 8) {
    // fp16 transpose of input weights for MFMA B-fragment vector loads
    const float* S = (blockIdx.x == 6) ? W1r_of : W1l_rev;
    _Float16* D    = (blockIdx.x == 6) ? W1rT16 : W1lrT16;
    for (int k = w * 16; k < w * 16 + 16; k++)
      D[(long)lane * H + k] = (_Float16)S[(long)k * H + lane];
  } else {
    // dense: Ylh = emb_loc @ W1l_of (fp16 out), grid-stride 4 rows/wave
    float wreg[H];
#pragma unroll
    for (int k = 0; k < H; k++) wreg[k] = W1l_of[k * H + lane];
    const int gw2 = (blockIdx.x - 8) * 4 + w;       // 0..4999
    for (int r = gw2; r < NLOC; r += 5000) {
      const float xv = emb_loc[(long)r * H + lane];
      float a0 = 0.f, a1 = 0.f;
#pragma unroll
      for (int k = 0; k < H; k += 2) {
        a0 += bcastf(xv, k)     * wreg[k];
        a1 += bcastf(xv, k + 1) * wreg[k + 1];
      }
      Ylh[(long)r * H + lane] = (_Float16)(a0 + a1);
    }
  }
}

// out16 = x @ W (no bias); fp32 in, fp16 out.
__global__ __launch_bounds__(256, 4) void dense_linear_kernel(
    const float* __restrict__ x, _Float16* __restrict__ out16,
    const float* __restrict__ W, int n)
{
  const int lane = threadIdx.x & 63;
  const int gw = (blockIdx.x * 256 + threadIdx.x) >> 6;
  const int nw = (gridDim.x * 256) >> 6;
  float w[H];
#pragma unroll
  for (int k = 0; k < H; k++) w[k] = W[k * H + lane];
  for (int i = gw; i < n; i += nw) {
    const float xv = x[i * H + lane];
    float a0 = 0.f, a1 = 0.f;
#pragma unroll
    for (int k = 0; k < H; k += 2) {
      a0 += bcastf(xv, k)     * w[k];
      a1 += bcastf(xv, k + 1) * w[k + 1];
    }
    out16[i * H + lane] = (_Float16)(a0 + a1);
  }
}

// Exp-side MFMA pass (dual-B, optional gather/bias/relu). Block = 16 rows.
// Quad-row gather: one wave-load (f16x4/lane) fetches FOUR neighbor rows
// (group g = lane>>4 selects neighbor, lane&15 the 8B row slice).
// Branch-free: clamped bcasti + masked fma (wave-uniform trip counts).
// B-fragments from fp16 pre-transposed weights.
__global__ __launch_bounds__(256, 4) void mfma_pass_kernel(
    const u16* __restrict__ nbr, const int* __restrict__ cnt,
    const _Float16* __restrict__ y,
    const float* a32, const _Float16* a16,
    _Float16* out1, const _Float16* __restrict__ W1T,
    const float* __restrict__ bias, int relu,
    _Float16* out2, const _Float16* __restrict__ W2T)
{
  const int w = threadIdx.x >> 6;
  const int lane = threadIdx.x & 63;
  const int q = lane >> 4;
  const int cidx = lane & 15;
  const int rb = blockIdx.x * 16;

  __shared__ float Gs[16 * 68];

  const _Float16* bt1 = W1T + (long)(w * 16 + cidx) * H;
  f16x8 b1lo = *(const f16x8*)(bt1 + q * 8);
  f16x8 b1hi = *(const f16x8*)(bt1 + 32 + q * 8);
  f16x8 b2lo, b2hi;
  if (out2) {
    const _Float16* bt2 = W2T + (long)(w * 16 + cidx) * H;
    b2lo = *(const f16x8*)(bt2 + q * 8);
    b2hi = *(const f16x8*)(bt2 + 32 + q * 8);
  }

  // A-fragment load hoisted above the gather (independent; overlaps latency)
  f16x8 a0, a1;
  if (a16) {
    const _Float16* ar = a16 + (long)(rb + cidx) * H;
    a0 = *(const f16x8*)(ar + q * 8);
    a1 = *(const f16x8*)(ar + 32 + q * 8);
  } else {
    const float* ar = a32 + (long)(rb + cidx) * H;
    f32x4 v0 = *(const f32x4*)(ar + q * 8);
    f32x4 v1 = *(const f32x4*)(ar + q * 8 + 4);
    f32x4 v2 = *(const f32x4*)(ar + 32 + q * 8);
    f32x4 v3 = *(const f32x4*)(ar + 32 + q * 8 + 4);
#pragma unroll
    for (int j = 0; j < 4; j++) {
      a0[j] = (_Float16)v0[j];
      a0[j + 4] = (_Float16)v1[j];
      a1[j] = (_Float16)v2[j];
      a1[j + 4] = (_Float16)v3[j];
    }
  }

  if (y) {
    const int i0r = rb + w * 4;
    const int g = lane >> 4;
    const int sub = lane & 15;
    int c4v[4];
#pragma unroll
    for (int rr = 0; rr < 4; rr++) c4v[rr] = cnt[i0r + rr];
    int id4[4];
#pragma unroll
    for (int rr = 0; rr < 4; rr++) {
      const int c = min(c4v[rr], PAD_E);
      id4[rr] = (lane < c) ? (int)nbr[(long)(i0r + rr) * PAD_E + lane] : 0;
    }
#pragma unroll
    for (int rr = 0; rr < 4; rr++) {
      const int cc = min(c4v[rr], PAD_E);
      const int id = id4[rr];
      const int kl = cc - 1;
      float s0 = 0.f, s1 = 0.f, s2 = 0.f, s3 = 0.f;
      for (int k = 0; k < cc; k += 4) {
        const int n0 = bcasti(id, k);
        const int n1 = bcasti(id, min(k + 1, kl));
        const int n2 = bcasti(id, min(k + 2, kl));
        const int n3 = bcasti(id, min(k + 3, kl));
        const int ns = sel4(g, n0, n1, n2, n3);
        const f16x4 v = *(const f16x4*)(y + (long)ns * H + sub * 4);
        const float msk = (k + g < cc) ? 1.0f : 0.0f;
        s0 = fmaf(msk, (float)v[0], s0);
        s1 = fmaf(msk, (float)v[1], s1);
        s2 = fmaf(msk, (float)v[2], s2);
        s3 = fmaf(msk, (float)v[3], s3);
      }
      s0 += __shfl_xor(s0, 16); s0 += __shfl_xor(s0, 32);
      s1 += __shfl_xor(s1, 16); s1 += __shfl_xor(s1, 32);
      s2 += __shfl_xor(s2, 16); s2 += __shfl_xor(s2, 32);
      s3 += __shfl_xor(s3, 16); s3 += __shfl_xor(s3, 32);
      const float inv = 1.0f / fmaxf((float)c4v[rr], 1.0f);
      if (lane < 16) {
        float* gp = &Gs[(w * 4 + rr) * 68 + 4 * lane];
        gp[0] = s0 * inv; gp[1] = s1 * inv;
        gp[2] = s2 * inv; gp[3] = s3 * inv;
      }
    }
  }

  f32x4 acc1 = {0.f, 0.f, 0.f, 0.f};
  acc1 = __builtin_amdgcn_mfma_f32_16x16x32_f16(a0, b1lo, acc1, 0, 0, 0);
  acc1 = __builtin_amdgcn_mfma_f32_16x16x32_f16(a1, b1hi, acc1, 0, 0, 0);
  f32x4 acc2 = {0.f, 0.f, 0.f, 0.f};
  if (out2) {
    acc2 = __builtin_amdgcn_mfma_f32_16x16x32_f16(a0, b2lo, acc2, 0, 0, 0);
    acc2 = __builtin_amdgcn_mfma_f32_16x16x32_f16(a1, b2hi, acc2, 0, 0, 0);
  }

  const float bj = bias ? bias[w * 16 + cidx] : 0.f;
  __syncthreads();   // Gs ready; all A loads drained before in-place stores
#pragma unroll
  for (int reg = 0; reg < 4; reg++) {
    const int r = q * 4 + reg;
    float v = acc1[reg] + bj;
    if (y) v += Gs[r * 68 + w * 16 + cidx];
    if (relu) v = fmaxf(v, 0.f);
    out1[(long)(rb + r) * H + w * 16 + cidx] = (_Float16)v;
    if (out2)
      out2[(long)(rb + r) * H + w * 16 + cidx] = (_Float16)acc2[reg];
  }
}

// Loc side: out = mean-gather(fp16 T rows) + x @ Wr + bias (opt relu).
// Twin-quad gather (2 wave-loads fetch 8 neighbor rows per iteration).
// Masked fma, clamped bcasti, then shfl relayout back to lane=col.
__global__ __launch_bounds__(256, 4) void loc_gather_kernel(
    const int* __restrict__ nbr, const int* __restrict__ cnt,
    const _Float16* __restrict__ T, const float* __restrict__ x,
    float* __restrict__ out32, _Float16* __restrict__ out16,
    const float* __restrict__ Wr, const float* __restrict__ bias,
    int n, int relu)
{
  const int lane = threadIdx.x & 63;
  const int gw = (blockIdx.x * 256 + threadIdx.x) >> 6;
  const int nw = (gridDim.x * 256) >> 6;
  const int g = lane >> 4;
  const int sub = lane & 15;
  float wr[H];
#pragma unroll
  for (int k = 0; k < H; k++) wr[k] = Wr[k * H + lane];
  const float bj = bias[lane];
  for (int i = gw; i < n; i += nw) {
    const int c = cnt[i];
    const int cc = min(c, PAD_L);
    const int* nb = nbr + (long)i * PAD_L;
    float s0 = 0.f, s1 = 0.f, s2 = 0.f, s3 = 0.f;
    float s4 = 0.f, s5 = 0.f, s6 = 0.f, s7 = 0.f;
    int e = 0;
    while (e < cc) {
      const int m = min(cc - e, 64);
      const int id = (lane < m) ? nb[e + lane] : 0;
      const int ml = m - 1;
      for (int k = 0; k < m; k += 8) {
        const int a0i = bcasti(id, k);
        const int a1i = bcasti(id, min(k + 1, ml));
        const int a2i = bcasti(id, min(k + 2, ml));
        const int a3i = bcasti(id, min(k + 3, ml));
        const int nsA = sel4(g, a0i, a1i, a2i, a3i);
        const f16x4 vA = *(const f16x4*)(T + (long)nsA * H + sub * 4);
        const int b0i = bcasti(id, min(k + 4, ml));
        const int b1i = bcasti(id, min(k + 5, ml));
        const int b2i = bcasti(id, min(k + 6, ml));
        const int b3i = bcasti(id, min(k + 7, ml));
        const int nsB = sel4(g, b0i, b1i, b2i, b3i);
        const f16x4 vB = *(const f16x4*)(T + (long)nsB * H + sub * 4);
        const float mA = (k + g < m) ? 1.0f : 0.0f;
        const float mB = (k + 4 + g < m) ? 1.0f : 0.0f;
        s0 = fmaf(mA, (float)vA[0], s0);
        s1 = fmaf(mA, (float)vA[1], s1);
        s2 = fmaf(mA, (float)vA[2], s2);
        s3 = fmaf(mA, (float)vA[3], s3);
        s4 = fmaf(mB, (float)vB[0], s4);
        s5 = fmaf(mB, (float)vB[1], s5);
        s6 = fmaf(mB, (float)vB[2], s6);
        s7 = fmaf(mB, (float)vB[3], s7);
      }
      e += m;
    }
    s0 += s4; s1 += s5; s2 += s6; s3 += s7;
    s0 += __shfl_xor(s0, 16); s0 += __shfl_xor(s0, 32);
    s1 += __shfl_xor(s1, 16); s1 += __shfl_xor(s1, 32);
    s2 += __shfl_xor(s2, 16); s2 += __shfl_xor(s2, 32);
    s3 += __shfl_xor(s3, 16); s3 += __shfl_xor(s3, 32);
    // relayout 4-col -> lane=col: col j=lane lives in s_{j&3} at lane j>>2
    const int srcl = lane >> 2;
    const float v0 = __shfl(s0, srcl);
    const float v1 = __shfl(s1, srcl);
    const float v2 = __shfl(s2, srcl);
    const float v3 = __shfl(s3, srcl);
    const int r2 = lane & 3;
    const float sg = (r2 & 2) ? ((r2 & 1) ? v3 : v2) : ((r2 & 1) ? v1 : v0);
    const float agg = sg / fmaxf((float)c, 1.0f);
    const float xv = x[(long)i * H + lane];
    float a0 = 0.f, a1 = 0.f;
#pragma unroll
    for (int k = 0; k < H; k += 2) {
      a0 += bcastf(xv, k)     * wr[k];
      a1 += bcastf(xv, k + 1) * wr[k + 1];
    }
    float acc = agg + bj + a0 + a1;
    if (relu) acc = fmaxf(acc, 0.0f);
    if (out32) out32[(long)i * H + lane] = acc;
    else       out16[(long)i * H + lane] = (_Float16)acc;
  }
}

// out[e] = sum_j relu(P[r,j] + Q[c,j] + db1[j]) * dW2[j] + db2  (P,Q fp16)
// Quad-edge loads — one f16x4 wave-load fetches 4 edges' P rows.
__global__ __launch_bounds__(256, 4) void edge_kernel(
    const int* __restrict__ row, const int* __restrict__ col,
    const _Float16* __restrict__ P, const _Float16* __restrict__ Q,
    const float* __restrict__ db1, const float* __restrict__ dW2,
    const float* __restrict__ db2, float* __restrict__ out)
{
  const int lane = threadIdx.x & 63;
  const int gw = (blockIdx.x * 256 + threadIdx.x) >> 6;
  const int nw = (gridDim.x * 256) >> 6;
  const int g = lane >> 4;
  const int sub = lane & 15;
  const f32x4 bj4 = *(const f32x4*)(db1 + 4 * sub);
  const f32x4 w24 = *(const f32x4*)(dW2 + 4 * sub);
  const float b2 = db2[0];
  for (int e = gw * 4; e < NL; e += nw * 4) {
    const int r0 = row[e], r1 = row[e + 1], r2i = row[e + 2], r3 = row[e + 3];
    const int c0 = col[e], c1 = col[e + 1], c2i = col[e + 2], c3 = col[e + 3];
    const int rs = sel4(g, r0, r1, r2i, r3);
    const int cs = sel4(g, c0, c1, c2i, c3);
    const f16x4 pv = *(const f16x4*)(P + (long)rs * H + sub * 4);
    const f16x4 qv = *(const f16x4*)(Q + (long)cs * H + sub * 4);
    float h = fmaxf((float)pv[0] + (float)qv[0] + bj4[0], 0.f) * w24[0]
            + fmaxf((float)pv[1] + (float)qv[1] + bj4[1], 0.f) * w24[1]
            + fmaxf((float)pv[2] + (float)qv[2] + bj4[2], 0.f) * w24[2]
            + fmaxf((float)pv[3] + (float)qv[3] + bj4[3], 0.f) * w24[3];
    h += __shfl_xor(h, 1);
    h += __shfl_xor(h, 2);
    h += __shfl_xor(h, 4);
    h += __shfl_xor(h, 8);
    if (sub == 0) out[e + g] = h + b2;
  }
}

extern "C" void kernel_launch(void* const* d_in, const int* in_sizes, int n_in,
                              void* d_out, int out_size, void* d_ws, size_t ws_size,
                              hipStream_t stream) {
  const float* emb_loc = (const float*)d_in[0];
  const float* emb_exp = (const float*)d_in[1];
  const float* W1l_of  = (const float*)d_in[2];
  const float* b1_of   = (const float*)d_in[3];
  const float* W1r_of  = (const float*)d_in[4];
  const float* W1l_rev = (const float*)d_in[5];
  const float* b1_rev  = (const float*)d_in[6];
  const float* W1r_rev = (const float*)d_in[7];
  const float* W2l_of  = (const float*)d_in[8];
  const float* b2_of   = (const float*)d_in[9];
  const float* W2r_of  = (const float*)d_in[10];
  const float* W2l_rev = (const float*)d_in[11];
  const float* b2_rev  = (const float*)d_in[12];
  const float* W2r_rev = (const float*)d_in[13];
  const float* dW1     = (const float*)d_in[14];
  const float* db1     = (const float*)d_in[15];
  const float* dW2     = (const float*)d_in[16];
  const float* db2     = (const float*)d_in[17];
  const int*   edge_of = (const int*)d_in[18];
  const int*   eli     = (const int*)d_in[20];

  const int* src = edge_of;
  const int* dst = edge_of + NE;
  const int* row = eli;
  const int* col = eli + NL;

  if (ws_size < WS_NEED) return;

  char* ws = (char*)d_ws;
  int*            cnt_loc = (int*)(ws);
  int*            cnt_exp = (int*)(ws + 80000);
  int*            nbr_loc = (int*)(ws + 880064);
  unsigned short* nbr_exp = (unsigned short*)(ws + 11120064);
  _Float16*       Ylh     = (_Float16*)(ws + 23920064);
  _Float16*       Y2fh    = (_Float16*)(ws + 26480064);
  float*          z_loc   = (float*)(ws + 29040064);
  _Float16*       PH      = (_Float16*)(ws + 34160064);
  _Float16*       W1rT16  = (_Float16*)(ws + 36720064);
  _Float16*       W1lrT16 = (_Float16*)(ws + 36728256);
  _Float16*       WfqT16  = (_Float16*)(ws + 36736448);
  _Float16*       Wft2T16 = (_Float16*)(ws + 36744640);
  _Float16*       ZE      = (_Float16*)(ws + 39280064);
  _Float16*       TH      = (_Float16*)(ws + 64880064);
  // fill-time aliases over the TH region (dead until mfma pass #1)
  u32*            expQ    = (u32*)(ws + 64880064);
  u32*            locQ    = (u32*)(ws + 72220096);
  int*            qcnt    = (int*)(ws + 79551936);
  int*            flbk    = (int*)(ws + 79553552);
  u64*            flbkQ   = (u64*)(ws + 79554048);
  float*          Wf_q    = (float*)(ws + 90480064);
  float*          Wf_y2   = (float*)(ws + 90496448);
  float*          Wf_t2   = (float*)(ws + 90512832);
  float*          Wf_p    = (float*)(ws + 90529216);
  float*          bf_q    = (float*)(ws + 90545600);
  float*          bf_p    = (float*)(ws + 90545856);
  float*          out     = (float*)d_out;

  // zero queue counters + fallback counter only
  (void)hipMemsetAsync(ws + 79551936, 0, 2048, stream);

  // ---- CSR fill: bin -> build (full-line writes) ----
  bin_kernel<<<NBIN, 256, 0, stream>>>(src, dst, expQ, locQ, qcnt, flbk, flbkQ);
  build_kernel<<<NBE + NBL, 256, 0, stream>>>(expQ, locQ, qcnt,
      nbr_exp, nbr_loc, cnt_exp, cnt_loc);
  // fold(+f16 transposes) + fallback drain + W transposes + dense#1
  prep_kernel<<<1258, 256, 0, stream>>>(W2r_of, W2l_of, W2l_rev, W2r_rev,
                                        dW1, b2_of, b2_rev,
                                        Wf_q, Wf_y2, Wf_t2, Wf_p, bf_q, bf_p,
                                        flbk, flbkQ, nbr_exp, nbr_loc,
                                        cnt_exp, cnt_loc,
                                        emb_loc, Ylh, W1l_of,
                                        W1r_of, W1l_rev,
                                        W1rT16, W1lrT16, WfqT16, Wft2T16);

  // ---- layer 1 ----
  // passA: z_exph = relu(emb_exp@W1r_of + gatherE(Ylh) + b1_of); T1h = emb_exp@W1l_rev
  mfma_pass_kernel<<<NEXP / 16, 256, 0, stream>>>(nbr_exp, cnt_exp, Ylh,
      emb_exp, (const _Float16*)nullptr, ZE, W1rT16, b1_of, 1, TH, W1lrT16);
  loc_gather_kernel<<<2048, 256, 0, stream>>>(nbr_loc, cnt_loc, TH,
      emb_loc, z_loc, (_Float16*)nullptr, W1r_rev, b1_rev, NLOC, 1);

  // ---- layer 2 + decoder transforms (folded: no relu on layer 2) ----
  dense_linear_kernel<<<1280, 256, 0, stream>>>(z_loc, Y2fh, Wf_y2, NLOC);
  // passB: Qh = z_exph@Wf_q + gatherE(Y2fh) + bf_q (in-place over ZE);
  //        T2'h = z_exph@Wf_t2 (over TH; T1h consumed)
  mfma_pass_kernel<<<NEXP / 16, 256, 0, stream>>>(nbr_exp, cnt_exp, Y2fh,
      (const float*)nullptr, ZE, ZE, WfqT16, bf_q, 0, TH, Wft2T16);
  // PH = gatherL(T2'h) + z_loc@Wf_p + bf_p   (decoder-left, folded, fp16 out)
  loc_gather_kernel<<<2048, 256, 0, stream>>>(nbr_loc, cnt_loc, TH,
      z_loc, (float*)nullptr, PH, Wf_p, bf_p, NLOC, 0);

  // ---- decoder edge pass ----
  edge_kernel<<<2048, 256, 0, stream>>>(row, col, PH, ZE,
                                        db1, dW2, db2, out);
}